// Round 1
// baseline (6925.938 us; speedup 1.0000x reference)
//
#include <hip/hip_runtime.h>
#include <hip/hip_bf16.h>

#define DIN 256
#define HID 256
#define DOUT 64

// ---------------------------------------------------------------------------
// Degree computation: gcn deg (in-degree, +1 self-loop added later),
// mp deg (symmetric, non-self edges).
__global__ __launch_bounds__(256) void deg_kernel(const int* __restrict__ u,
                                                  const int* __restrict__ v,
                                                  float* __restrict__ deg_gcn,
                                                  float* __restrict__ deg_mp,
                                                  int E) {
    int e = blockIdx.x * blockDim.x + threadIdx.x;
    if (e >= E) return;
    int a = u[e], b = v[e];
    atomicAdd(&deg_gcn[b], 1.0f);
    if (a != b) {
        atomicAdd(&deg_mp[a], 1.0f);
        atomicAdd(&deg_mp[b], 1.0f);
    }
}

__global__ __launch_bounds__(256) void dis_kernel(float* __restrict__ dg,
                                                  float* __restrict__ dm,
                                                  int N) {
    int i = blockIdx.x * blockDim.x + threadIdx.x;
    if (i >= N) return;
    dg[i] = rsqrtf(dg[i] + 1.0f);          // self loop: deg >= 1 always
    float d = dm[i];
    dm[i] = (d > 0.0f) ? rsqrtf(d) : 0.0f;
}

// ---------------------------------------------------------------------------
// Tiled f32 GEMM: C[M x N] = op(A)[M x K] @ B[K x N] (+ bias)
// op(A) = relu(A) if RELU_A. 64x64 tile, 256 threads, 4x4 per thread.
template <bool RELU_A, bool ADD_BIAS>
__global__ __launch_bounds__(256) void gemm_kernel(const float* __restrict__ A,
                                                   const float* __restrict__ B,
                                                   const float* __restrict__ bias,
                                                   float* __restrict__ C,
                                                   int M, int N, int K) {
    __shared__ float As[64][17];
    __shared__ float Bs[16][65];
    const int tid = threadIdx.x;
    const int tx = tid & 15, ty = tid >> 4;
    const int row0 = blockIdx.x * 64;
    const int col0 = blockIdx.y * 64;
    float acc[4][4] = {};
    for (int k0 = 0; k0 < K; k0 += 16) {
#pragma unroll
        for (int i = 0; i < 4; ++i) {
            int idx = tid * 4 + i;  // 0..1023
            int r = idx >> 4, kk = idx & 15;
            int gr = row0 + r;
            float vA = (gr < M) ? A[(size_t)gr * K + k0 + kk] : 0.0f;
            if (RELU_A) vA = fmaxf(vA, 0.0f);
            As[r][kk] = vA;
            int kB = idx >> 6, cB = idx & 63;  // 16 x 64
            Bs[kB][cB] = B[(size_t)(k0 + kB) * N + col0 + cB];
        }
        __syncthreads();
#pragma unroll
        for (int kk = 0; kk < 16; ++kk) {
            float a[4], b[4];
#pragma unroll
            for (int i = 0; i < 4; ++i) a[i] = As[ty * 4 + i][kk];
#pragma unroll
            for (int j = 0; j < 4; ++j) b[j] = Bs[kk][tx * 4 + j];
#pragma unroll
            for (int i = 0; i < 4; ++i)
#pragma unroll
                for (int j = 0; j < 4; ++j) acc[i][j] += a[i] * b[j];
        }
        __syncthreads();
    }
#pragma unroll
    for (int i = 0; i < 4; ++i) {
        int gr = row0 + ty * 4 + i;
        if (gr >= M) continue;
#pragma unroll
        for (int j = 0; j < 4; ++j) {
            int gc = col0 + tx * 4 + j;
            float vv = acc[i][j];
            if (ADD_BIAS) vv += bias[gc];
            C[(size_t)gr * N + gc] = vv;
        }
    }
}

// ---------------------------------------------------------------------------
// agg[i][:] = dis[i]^2 * h[i][:] + bias[:]   (self-loop term + post bias)
__global__ __launch_bounds__(256) void agg_init_kernel(const float* __restrict__ h,
                                                       const float* __restrict__ dis,
                                                       const float* __restrict__ bias,
                                                       float* __restrict__ agg,
                                                       int N) {
    int i = blockIdx.x * blockDim.x + threadIdx.x;  // over N * 64 float4s
    if (i >= N * (DIN / 4)) return;
    int node = i >> 6;
    int j4 = i & 63;
    float s = dis[node];
    s *= s;
    float4 hv = ((const float4*)h)[i];
    float4 bv = ((const float4*)bias)[j4];
    float4 o;
    o.x = s * hv.x + bv.x;
    o.y = s * hv.y + bv.y;
    o.z = s * hv.z + bv.z;
    o.w = s * hv.w + bv.w;
    ((float4*)agg)[i] = o;
}

// agg[v] += dis[u]*dis[v] * h[u]   (one wave per edge, 256 floats = 64 x float4)
__global__ __launch_bounds__(256) void agg_edge_kernel(const int* __restrict__ u,
                                                       const int* __restrict__ v,
                                                       const float* __restrict__ dis,
                                                       const float* __restrict__ h,
                                                       float* __restrict__ agg,
                                                       int E) {
    int wid = (blockIdx.x * blockDim.x + threadIdx.x) >> 6;
    int lane = threadIdx.x & 63;
    if (wid >= E) return;
    int a = u[wid], b = v[wid];
    float s = dis[a] * dis[b];
    float4 hv = ((const float4*)(h + (size_t)a * DIN))[lane];
    float* dst = agg + (size_t)b * DIN + lane * 4;
    atomicAdd(dst + 0, s * hv.x);
    atomicAdd(dst + 1, s * hv.y);
    atomicAdd(dst + 2, s * hv.z);
    atomicAdd(dst + 3, s * hv.w);
}

// Message passing: both directions, 64-dim, one wave per edge.
__global__ __launch_bounds__(256) void mp_edge_kernel(const int* __restrict__ u,
                                                      const int* __restrict__ v,
                                                      const float* __restrict__ dis,
                                                      const float* __restrict__ in,
                                                      float* __restrict__ out,
                                                      int E) {
    int wid = (blockIdx.x * blockDim.x + threadIdx.x) >> 6;
    int lane = threadIdx.x & 63;
    if (wid >= E) return;
    int a = u[wid], b = v[wid];
    if (a == b) return;
    float s = dis[a] * dis[b];
    float va = in[(size_t)a * DOUT + lane];
    float vb = in[(size_t)b * DOUT + lane];
    atomicAdd(out + (size_t)b * DOUT + lane, s * va);
    atomicAdd(out + (size_t)a * DOUT + lane, s * vb);
}

// ---------------------------------------------------------------------------
// Loss: wave per triplet row (wave-stride), 5 butterfly reductions.
__global__ __launch_bounds__(256) void loss_kernel(const float* __restrict__ emb,
                                                   const int* __restrict__ batch,
                                                   float* __restrict__ out,
                                                   int B, float invB) {
    const int nwaves = gridDim.x * 4;
    const int wid = blockIdx.x * 4 + (threadIdx.x >> 6);
    const int lane = threadIdx.x & 63;
    float lsum = 0.0f;
    for (int r = wid; r < B; r += nwaves) {
        int a = batch[r * 3 + 0];
        int p = batch[r * 3 + 1];
        int ng = batch[r * 3 + 2];
        float va = emb[(size_t)a * DOUT + lane];
        float vp = emb[(size_t)p * DOUT + lane];
        float vn = emb[(size_t)ng * DOUT + lane];
        float aa = va * va, pp = vp * vp, nn = vn * vn;
        float ap = va * vp, an = va * vn;
#pragma unroll
        for (int off = 32; off > 0; off >>= 1) {
            aa += __shfl_xor(aa, off);
            pp += __shfl_xor(pp, off);
            nn += __shfl_xor(nn, off);
            ap += __shfl_xor(ap, off);
            an += __shfl_xor(an, off);
        }
        if (lane == 0) {
            float na = fmaxf(sqrtf(aa), 1e-8f);
            float npp = fmaxf(sqrtf(pp), 1e-8f);
            float nnn = fmaxf(sqrtf(nn), 1e-8f);
            float cx = ap / (na * npp);
            float cy = an / (na * nnn);
            lsum += log1pf(expf((cy - cx) * 5.0f));  // 1/TEMP = 5
        }
    }
    __shared__ float part[4];
    if (lane == 0) part[threadIdx.x >> 6] = lsum;
    __syncthreads();
    if (threadIdx.x == 0)
        atomicAdd(out, (part[0] + part[1] + part[2] + part[3]) * invB);
}

// ---------------------------------------------------------------------------
extern "C" void kernel_launch(void* const* d_in, const int* in_sizes, int n_in,
                              void* d_out, int out_size, void* d_ws, size_t ws_size,
                              hipStream_t stream) {
    const float* x  = (const float*)d_in[0];
    const int* ei   = (const int*)d_in[1];
    const int* batch = (const int*)d_in[2];
    const float* W1 = (const float*)d_in[3];
    const float* b1 = (const float*)d_in[4];
    const float* W2 = (const float*)d_in[5];
    const float* b2 = (const float*)d_in[6];
    const float* Wp = (const float*)d_in[7];
    const float* bp = (const float*)d_in[8];
    const int N = in_sizes[0] / DIN;
    const int E = in_sizes[1] / 2;
    const int B = in_sizes[2] / 3;
    const int* u = ei;
    const int* v = ei + E;

    float* ws = (float*)d_ws;
    float* h    = ws;                       // N*256
    float* agg  = h + (size_t)N * DIN;      // N*256
    float* emb0 = agg + (size_t)N * DIN;    // N*64
    float* emb1 = emb0 + (size_t)N * DOUT;  // N*64
    float* disg = emb1 + (size_t)N * DOUT;  // N
    float* dism = disg + N;                 // N

    // --- degrees / normalizers
    hipMemsetAsync(disg, 0, (size_t)N * sizeof(float), stream);
    hipMemsetAsync(dism, 0, (size_t)N * sizeof(float), stream);
    deg_kernel<<<(E + 255) / 256, 256, 0, stream>>>(u, v, disg, dism, E);
    dis_kernel<<<(N + 255) / 256, 256, 0, stream>>>(disg, dism, N);

    const int ewaves_blocks = (E + 3) / 4;       // 4 waves (edges) per block
    const int gm = (N + 63) / 64;

    // --- conv1: h = x @ W1 ; agg = dis^2*h + b1 ; edge scatter
    gemm_kernel<false, false><<<dim3(gm, HID / 64), 256, 0, stream>>>(x, W1, nullptr, h, N, HID, DIN);
    agg_init_kernel<<<(N * (DIN / 4) + 255) / 256, 256, 0, stream>>>(h, disg, b1, agg, N);
    agg_edge_kernel<<<ewaves_blocks, 256, 0, stream>>>(u, v, disg, h, agg, E);

    // --- conv2: h = relu(agg) @ W2 ; agg = dis^2*h + b2 ; edge scatter
    gemm_kernel<true, false><<<dim3(gm, HID / 64), 256, 0, stream>>>(agg, W2, nullptr, h, N, HID, HID);
    agg_init_kernel<<<(N * (DIN / 4) + 255) / 256, 256, 0, stream>>>(h, disg, b2, agg, N);
    agg_edge_kernel<<<ewaves_blocks, 256, 0, stream>>>(u, v, disg, h, agg, E);

    // --- projection: emb0 = agg @ Wp + bp
    gemm_kernel<false, true><<<dim3(gm, DOUT / 64), 256, 0, stream>>>(agg, Wp, bp, emb0, N, DOUT, HID);

    // --- 2-hop message passing (symmetric, no self loops)
    hipMemsetAsync(emb1, 0, (size_t)N * DOUT * sizeof(float), stream);
    mp_edge_kernel<<<ewaves_blocks, 256, 0, stream>>>(u, v, dism, emb0, emb1, E);
    hipMemsetAsync(emb0, 0, (size_t)N * DOUT * sizeof(float), stream);
    mp_edge_kernel<<<ewaves_blocks, 256, 0, stream>>>(u, v, dism, emb1, emb0, E);

    // --- loss
    hipMemsetAsync(d_out, 0, sizeof(float), stream);
    loss_kernel<<<1024, 256, 0, stream>>>(emb0, batch, (float*)d_out, B, 1.0f / (float)B);
}

// Round 2
// 1665.872 us; speedup vs baseline: 4.1575x; 4.1575x over previous
//
#include <hip/hip_runtime.h>
#include <hip/hip_bf16.h>

#define DIN 256
#define HID 256
#define DOUT 64

// ---------------------------------------------------------------------------
// Integer degree counting. cnt_g: GCN in-degree (per v, self-edges counted as
// regular edges). cnt_m: symmetric MP degree (non-self edges, both ends).
__global__ __launch_bounds__(256) void deg_kernel(const int* __restrict__ u,
                                                  const int* __restrict__ v,
                                                  int* __restrict__ cnt_g,
                                                  int* __restrict__ cnt_m,
                                                  int E) {
    int e = blockIdx.x * blockDim.x + threadIdx.x;
    if (e >= E) return;
    int a = u[e], b = v[e];
    atomicAdd(&cnt_g[b], 1);
    if (a != b) {
        atomicAdd(&cnt_m[a], 1);
        atomicAdd(&cnt_m[b], 1);
    }
}

// dis_g = rsqrt(deg_g + 1)  (the +1 is the self loop)
// dis_m = deg_m > 0 ? rsqrt(deg_m) : 0
__global__ __launch_bounds__(256) void dis_kernel(const int* __restrict__ cnt_g,
                                                  const int* __restrict__ cnt_m,
                                                  float* __restrict__ dis_g,
                                                  float* __restrict__ dis_m,
                                                  int N) {
    int i = blockIdx.x * blockDim.x + threadIdx.x;
    if (i >= N) return;
    dis_g[i] = rsqrtf((float)cnt_g[i] + 1.0f);
    int d = cnt_m[i];
    dis_m[i] = (d > 0) ? rsqrtf((float)d) : 0.0f;
}

// ---------------------------------------------------------------------------
// 3-phase exclusive scan for two int arrays at once (N ~ 100k).
__global__ __launch_bounds__(256) void scan_reduce_kernel(const int* __restrict__ a,
                                                          const int* __restrict__ b,
                                                          int* __restrict__ bsa,
                                                          int* __restrict__ bsb,
                                                          int N) {
    __shared__ int sa[256], sb[256];
    int i = blockIdx.x * 256 + threadIdx.x;
    sa[threadIdx.x] = (i < N) ? a[i] : 0;
    sb[threadIdx.x] = (i < N) ? b[i] : 0;
    __syncthreads();
    for (int s = 128; s > 0; s >>= 1) {
        if (threadIdx.x < s) {
            sa[threadIdx.x] += sa[threadIdx.x + s];
            sb[threadIdx.x] += sb[threadIdx.x + s];
        }
        __syncthreads();
    }
    if (threadIdx.x == 0) { bsa[blockIdx.x] = sa[0]; bsb[blockIdx.x] = sb[0]; }
}

__global__ void scan_bsum_kernel(int* __restrict__ bsa, int* __restrict__ bsb, int nb) {
    if (threadIdx.x == 0) {
        int acc = 0;
        for (int i = 0; i < nb; ++i) { int t = bsa[i]; bsa[i] = acc; acc += t; }
    }
    if (threadIdx.x == 1) {
        int acc = 0;
        for (int i = 0; i < nb; ++i) { int t = bsb[i]; bsb[i] = acc; acc += t; }
    }
}

// Writes rp[i+1] = inclusive_scan(deg)[i] (+ block offset); rp[0] = 0.
__global__ __launch_bounds__(256) void scan_final_kernel(const int* __restrict__ a,
                                                         const int* __restrict__ b,
                                                         const int* __restrict__ bsa,
                                                         const int* __restrict__ bsb,
                                                         int* __restrict__ rpa,
                                                         int* __restrict__ rpb,
                                                         int N) {
    __shared__ int sa[256], sb[256];
    int i = blockIdx.x * 256 + threadIdx.x;
    sa[threadIdx.x] = (i < N) ? a[i] : 0;
    sb[threadIdx.x] = (i < N) ? b[i] : 0;
    __syncthreads();
    for (int off = 1; off < 256; off <<= 1) {
        int ta = (threadIdx.x >= off) ? sa[threadIdx.x - off] : 0;
        int tb = (threadIdx.x >= off) ? sb[threadIdx.x - off] : 0;
        __syncthreads();
        sa[threadIdx.x] += ta;
        sb[threadIdx.x] += tb;
        __syncthreads();
    }
    if (i < N) {
        rpa[i + 1] = bsa[blockIdx.x] + sa[threadIdx.x];
        rpb[i + 1] = bsb[blockIdx.x] + sb[threadIdx.x];
    }
    if (i == 0) { rpa[0] = 0; rpb[0] = 0; }
}

// ---------------------------------------------------------------------------
// CSR fill. GCN: edges bucketed by destination v. MP: both directions, no self.
__global__ __launch_bounds__(256) void fill_kernel(const int* __restrict__ u,
                                                   const int* __restrict__ v,
                                                   const int* __restrict__ rp_g,
                                                   const int* __restrict__ rp_m,
                                                   int* __restrict__ cnt_g,
                                                   int* __restrict__ cnt_m,
                                                   int* __restrict__ col_g,
                                                   int* __restrict__ col_m,
                                                   int E) {
    int e = blockIdx.x * blockDim.x + threadIdx.x;
    if (e >= E) return;
    int a = u[e], b = v[e];
    int p = rp_g[b] + atomicAdd(&cnt_g[b], 1);
    col_g[p] = a;
    if (a != b) {
        int p1 = rp_m[b] + atomicAdd(&cnt_m[b], 1);
        col_m[p1] = a;
        int p2 = rp_m[a] + atomicAdd(&cnt_m[a], 1);
        col_m[p2] = b;
    }
}

// ---------------------------------------------------------------------------
// Tiled f32 GEMM: C[M x N] = op(A)[M x K] @ B[K x N] (+ bias)
template <bool RELU_A, bool ADD_BIAS>
__global__ __launch_bounds__(256) void gemm_kernel(const float* __restrict__ A,
                                                   const float* __restrict__ B,
                                                   const float* __restrict__ bias,
                                                   float* __restrict__ C,
                                                   int M, int N, int K) {
    __shared__ float As[64][17];
    __shared__ float Bs[16][65];
    const int tid = threadIdx.x;
    const int tx = tid & 15, ty = tid >> 4;
    const int row0 = blockIdx.x * 64;
    const int col0 = blockIdx.y * 64;
    float acc[4][4] = {};
    for (int k0 = 0; k0 < K; k0 += 16) {
#pragma unroll
        for (int i = 0; i < 4; ++i) {
            int idx = tid * 4 + i;  // 0..1023
            int r = idx >> 4, kk = idx & 15;
            int gr = row0 + r;
            float vA = (gr < M) ? A[(size_t)gr * K + k0 + kk] : 0.0f;
            if (RELU_A) vA = fmaxf(vA, 0.0f);
            As[r][kk] = vA;
            int kB = idx >> 6, cB = idx & 63;  // 16 x 64
            Bs[kB][cB] = B[(size_t)(k0 + kB) * N + col0 + cB];
        }
        __syncthreads();
#pragma unroll
        for (int kk = 0; kk < 16; ++kk) {
            float a[4], b[4];
#pragma unroll
            for (int i = 0; i < 4; ++i) a[i] = As[ty * 4 + i][kk];
#pragma unroll
            for (int j = 0; j < 4; ++j) b[j] = Bs[kk][tx * 4 + j];
#pragma unroll
            for (int i = 0; i < 4; ++i)
#pragma unroll
                for (int j = 0; j < 4; ++j) acc[i][j] += a[i] * b[j];
        }
        __syncthreads();
    }
#pragma unroll
    for (int i = 0; i < 4; ++i) {
        int gr = row0 + ty * 4 + i;
        if (gr >= M) continue;
#pragma unroll
        for (int j = 0; j < 4; ++j) {
            int gc = col0 + tx * 4 + j;
            float vv = acc[i][j];
            if (ADD_BIAS) vv += bias[gc];
            C[(size_t)gr * N + gc] = vv;
        }
    }
}

// ---------------------------------------------------------------------------
// GCN aggregation by gather: one wave per node, lane owns one float4 (D=256).
// agg[i] = dis[i]^2 * h[i] + bias + sum_{e: v=i} dis[i]*dis[u_e] * h[u_e]
__global__ __launch_bounds__(256) void conv_gather_kernel(const float* __restrict__ h,
                                                          const float* __restrict__ dis,
                                                          const float* __restrict__ bias,
                                                          const int* __restrict__ rp,
                                                          const int* __restrict__ col,
                                                          float* __restrict__ agg,
                                                          int N) {
    int wid = (blockIdx.x * blockDim.x + threadIdx.x) >> 6;
    int lane = threadIdx.x & 63;
    if (wid >= N) return;
    float di = dis[wid];
    const float4* h4 = (const float4*)h;
    float4 hv = h4[(size_t)wid * 64 + lane];
    float4 bv = ((const float4*)bias)[lane];
    float s2 = di * di;
    float4 acc;
    acc.x = s2 * hv.x + bv.x;
    acc.y = s2 * hv.y + bv.y;
    acc.z = s2 * hv.z + bv.z;
    acc.w = s2 * hv.w + bv.w;
    int e0 = rp[wid], e1 = rp[wid + 1];
    for (int e = e0; e < e1; ++e) {
        int s = col[e];
        float c = di * dis[s];
        float4 nv = h4[(size_t)s * 64 + lane];
        acc.x += c * nv.x;
        acc.y += c * nv.y;
        acc.z += c * nv.z;
        acc.w += c * nv.w;
    }
    ((float4*)agg)[(size_t)wid * 64 + lane] = acc;
}

// Message passing by gather: one wave per node, lane owns one float (D=64).
__global__ __launch_bounds__(256) void mp_gather_kernel(const float* __restrict__ in,
                                                        const float* __restrict__ dis,
                                                        const int* __restrict__ rp,
                                                        const int* __restrict__ col,
                                                        float* __restrict__ out,
                                                        int N) {
    int wid = (blockIdx.x * blockDim.x + threadIdx.x) >> 6;
    int lane = threadIdx.x & 63;
    if (wid >= N) return;
    float di = dis[wid];
    float acc = 0.0f;
    int e0 = rp[wid], e1 = rp[wid + 1];
    for (int e = e0; e < e1; ++e) {
        int s = col[e];
        acc += di * dis[s] * in[(size_t)s * DOUT + lane];
    }
    out[(size_t)wid * DOUT + lane] = acc;
}

// ---------------------------------------------------------------------------
// Loss: wave per triplet row (wave-stride), 5 butterfly reductions.
__global__ __launch_bounds__(256) void loss_kernel(const float* __restrict__ emb,
                                                   const int* __restrict__ batch,
                                                   float* __restrict__ out,
                                                   int B, float invB) {
    const int nwaves = gridDim.x * 4;
    const int wid = blockIdx.x * 4 + (threadIdx.x >> 6);
    const int lane = threadIdx.x & 63;
    float lsum = 0.0f;
    for (int r = wid; r < B; r += nwaves) {
        int a = batch[r * 3 + 0];
        int p = batch[r * 3 + 1];
        int ng = batch[r * 3 + 2];
        float va = emb[(size_t)a * DOUT + lane];
        float vp = emb[(size_t)p * DOUT + lane];
        float vn = emb[(size_t)ng * DOUT + lane];
        float aa = va * va, pp = vp * vp, nn = vn * vn;
        float ap = va * vp, an = va * vn;
#pragma unroll
        for (int off = 32; off > 0; off >>= 1) {
            aa += __shfl_xor(aa, off);
            pp += __shfl_xor(pp, off);
            nn += __shfl_xor(nn, off);
            ap += __shfl_xor(ap, off);
            an += __shfl_xor(an, off);
        }
        if (lane == 0) {
            float na = fmaxf(sqrtf(aa), 1e-8f);
            float npp = fmaxf(sqrtf(pp), 1e-8f);
            float nnn = fmaxf(sqrtf(nn), 1e-8f);
            float cx = ap / (na * npp);
            float cy = an / (na * nnn);
            lsum += log1pf(expf((cy - cx) * 5.0f));  // 1/TEMP = 5
        }
    }
    __shared__ float part[4];
    if (lane == 0) part[threadIdx.x >> 6] = lsum;
    __syncthreads();
    if (threadIdx.x == 0)
        atomicAdd(out, (part[0] + part[1] + part[2] + part[3]) * invB);
}

// ---------------------------------------------------------------------------
extern "C" void kernel_launch(void* const* d_in, const int* in_sizes, int n_in,
                              void* d_out, int out_size, void* d_ws, size_t ws_size,
                              hipStream_t stream) {
    const float* x   = (const float*)d_in[0];
    const int* ei    = (const int*)d_in[1];
    const int* batch = (const int*)d_in[2];
    const float* W1  = (const float*)d_in[3];
    const float* b1  = (const float*)d_in[4];
    const float* W2  = (const float*)d_in[5];
    const float* b2  = (const float*)d_in[6];
    const float* Wp  = (const float*)d_in[7];
    const float* bp  = (const float*)d_in[8];
    const int N = in_sizes[0] / DIN;
    const int E = in_sizes[1] / 2;
    const int B = in_sizes[2] / 3;
    const int* u = ei;
    const int* v = ei + E;

    // --- workspace layout (~217 MB) ---
    float* h     = (float*)d_ws;            // N*256 (later reused for emb0/emb1)
    float* agg   = h + (size_t)N * DIN;     // N*256
    float* dis_g = agg + (size_t)N * DIN;   // N
    float* dis_m = dis_g + N;               // N
    int* rp_g  = (int*)(dis_m + N);         // N+1
    int* rp_m  = rp_g + (N + 1);            // N+1
    int* cnt_g = rp_m + (N + 1);            // N (deg, then fill counter)
    int* cnt_m = cnt_g + N;                 // N
    int* col_g = cnt_m + N;                 // E
    int* col_m = col_g + E;                 // 2E
    int* bsum_g = col_m + 2 * (size_t)E;    // nb
    const int nb = (N + 255) / 256;
    int* bsum_m = bsum_g + nb;              // nb
    float* emb0 = h;                        // N*64 (aliases h, free after conv2)
    float* emb1 = h + (size_t)N * DOUT;     // N*64

    const int eb = (E + 255) / 256;
    const int nwb = (N + 3) / 4;  // gather kernels: 4 waves (nodes) per block
    const int gm = (N + 63) / 64;

    // --- degrees, normalizers, CSR build ---
    hipMemsetAsync(cnt_g, 0, (size_t)N * sizeof(int), stream);
    hipMemsetAsync(cnt_m, 0, (size_t)N * sizeof(int), stream);
    deg_kernel<<<eb, 256, 0, stream>>>(u, v, cnt_g, cnt_m, E);
    dis_kernel<<<(N + 255) / 256, 256, 0, stream>>>(cnt_g, cnt_m, dis_g, dis_m, N);
    scan_reduce_kernel<<<nb, 256, 0, stream>>>(cnt_g, cnt_m, bsum_g, bsum_m, N);
    scan_bsum_kernel<<<1, 64, 0, stream>>>(bsum_g, bsum_m, nb);
    scan_final_kernel<<<nb, 256, 0, stream>>>(cnt_g, cnt_m, bsum_g, bsum_m, rp_g, rp_m, N);
    hipMemsetAsync(cnt_g, 0, (size_t)N * sizeof(int), stream);
    hipMemsetAsync(cnt_m, 0, (size_t)N * sizeof(int), stream);
    fill_kernel<<<eb, 256, 0, stream>>>(u, v, rp_g, rp_m, cnt_g, cnt_m, col_g, col_m, E);

    // --- conv1: h = x @ W1 ; agg = gather(h) + b1 ---
    gemm_kernel<false, false><<<dim3(gm, HID / 64), 256, 0, stream>>>(x, W1, nullptr, h, N, HID, DIN);
    conv_gather_kernel<<<nwb, 256, 0, stream>>>(h, dis_g, b1, rp_g, col_g, agg, N);

    // --- conv2: h = relu(agg) @ W2 ; agg = gather(h) + b2 ---
    gemm_kernel<true, false><<<dim3(gm, HID / 64), 256, 0, stream>>>(agg, W2, nullptr, h, N, HID, HID);
    conv_gather_kernel<<<nwb, 256, 0, stream>>>(h, dis_g, b2, rp_g, col_g, agg, N);

    // --- projection: emb0 = agg @ Wp + bp  (emb0 aliases h; h is dead) ---
    gemm_kernel<false, true><<<dim3(gm, DOUT / 64), 256, 0, stream>>>(agg, Wp, bp, emb0, N, DOUT, HID);

    // --- 2-hop message passing (gather, no atomics, full overwrite) ---
    mp_gather_kernel<<<nwb, 256, 0, stream>>>(emb0, dis_m, rp_m, col_m, emb1, N);
    mp_gather_kernel<<<nwb, 256, 0, stream>>>(emb1, dis_m, rp_m, col_m, emb0, N);

    // --- loss ---
    hipMemsetAsync(d_out, 0, sizeof(float), stream);
    loss_kernel<<<1024, 256, 0, stream>>>(emb0, batch, (float*)d_out, B, 1.0f / (float)B);
}

// Round 3
// 1056.530 us; speedup vs baseline: 6.5554x; 1.5767x over previous
//
#include <hip/hip_runtime.h>
#include <hip/hip_bf16.h>

#define DIN 256
#define HID 256
#define DOUT 64

typedef short short8 __attribute__((ext_vector_type(8)));
typedef float f32x4 __attribute__((ext_vector_type(4)));

__device__ __forceinline__ float b2f(ushort u) {
    unsigned int x = ((unsigned int)u) << 16;
    return __builtin_bit_cast(float, x);
}
__device__ __forceinline__ ushort f2bf(float f) {
    unsigned int u = __builtin_bit_cast(unsigned int, f);
    unsigned int r = (u + 0x7FFFu + ((u >> 16) & 1u)) >> 16;
    return (ushort)r;
}
__device__ __forceinline__ void gload16(const void* g, void* l) {
    __builtin_amdgcn_global_load_lds(
        (const __attribute__((address_space(1))) unsigned int*)g,
        (__attribute__((address_space(3))) unsigned int*)l, 16, 0, 0);
}

// ---------------------------------------------------------------------------
// Degree counting (int atomics).
__global__ __launch_bounds__(256) void deg_kernel(const int* __restrict__ u,
                                                  const int* __restrict__ v,
                                                  int* __restrict__ cnt_g,
                                                  int* __restrict__ cnt_m,
                                                  int E) {
    int e = blockIdx.x * blockDim.x + threadIdx.x;
    if (e >= E) return;
    int a = u[e], b = v[e];
    atomicAdd(&cnt_g[b], 1);
    if (a != b) {
        atomicAdd(&cnt_m[a], 1);
        atomicAdd(&cnt_m[b], 1);
    }
}

__global__ __launch_bounds__(256) void dis_kernel(const int* __restrict__ cnt_g,
                                                  const int* __restrict__ cnt_m,
                                                  float* __restrict__ dis_g,
                                                  float* __restrict__ dis_m,
                                                  int N) {
    int i = blockIdx.x * blockDim.x + threadIdx.x;
    if (i >= N) return;
    dis_g[i] = rsqrtf((float)cnt_g[i] + 1.0f);
    int d = cnt_m[i];
    dis_m[i] = (d > 0) ? rsqrtf((float)d) : 0.0f;
}

// ---------------------------------------------------------------------------
// 3-phase exclusive scan for two int arrays at once.
__global__ __launch_bounds__(256) void scan_reduce_kernel(const int* __restrict__ a,
                                                          const int* __restrict__ b,
                                                          int* __restrict__ bsa,
                                                          int* __restrict__ bsb,
                                                          int N) {
    __shared__ int sa[256], sb[256];
    int i = blockIdx.x * 256 + threadIdx.x;
    sa[threadIdx.x] = (i < N) ? a[i] : 0;
    sb[threadIdx.x] = (i < N) ? b[i] : 0;
    __syncthreads();
    for (int s = 128; s > 0; s >>= 1) {
        if (threadIdx.x < s) {
            sa[threadIdx.x] += sa[threadIdx.x + s];
            sb[threadIdx.x] += sb[threadIdx.x + s];
        }
        __syncthreads();
    }
    if (threadIdx.x == 0) { bsa[blockIdx.x] = sa[0]; bsb[blockIdx.x] = sb[0]; }
}

__global__ void scan_bsum_kernel(int* __restrict__ bsa, int* __restrict__ bsb, int nb) {
    if (threadIdx.x == 0) {
        int acc = 0;
        for (int i = 0; i < nb; ++i) { int t = bsa[i]; bsa[i] = acc; acc += t; }
    }
    if (threadIdx.x == 1) {
        int acc = 0;
        for (int i = 0; i < nb; ++i) { int t = bsb[i]; bsb[i] = acc; acc += t; }
    }
}

__global__ __launch_bounds__(256) void scan_final_kernel(const int* __restrict__ a,
                                                         const int* __restrict__ b,
                                                         const int* __restrict__ bsa,
                                                         const int* __restrict__ bsb,
                                                         int* __restrict__ rpa,
                                                         int* __restrict__ rpb,
                                                         int N) {
    __shared__ int sa[256], sb[256];
    int i = blockIdx.x * 256 + threadIdx.x;
    sa[threadIdx.x] = (i < N) ? a[i] : 0;
    sb[threadIdx.x] = (i < N) ? b[i] : 0;
    __syncthreads();
    for (int off = 1; off < 256; off <<= 1) {
        int ta = (threadIdx.x >= off) ? sa[threadIdx.x - off] : 0;
        int tb = (threadIdx.x >= off) ? sb[threadIdx.x - off] : 0;
        __syncthreads();
        sa[threadIdx.x] += ta;
        sb[threadIdx.x] += tb;
        __syncthreads();
    }
    if (i < N) {
        rpa[i + 1] = bsa[blockIdx.x] + sa[threadIdx.x];
        rpb[i + 1] = bsb[blockIdx.x] + sb[threadIdx.x];
    }
    if (i == 0) { rpa[0] = 0; rpb[0] = 0; }
}

// ---------------------------------------------------------------------------
// CSR fill.
__global__ __launch_bounds__(256) void fill_kernel(const int* __restrict__ u,
                                                   const int* __restrict__ v,
                                                   const int* __restrict__ rp_g,
                                                   const int* __restrict__ rp_m,
                                                   int* __restrict__ cnt_g,
                                                   int* __restrict__ cnt_m,
                                                   int* __restrict__ col_g,
                                                   int* __restrict__ col_m,
                                                   int E) {
    int e = blockIdx.x * blockDim.x + threadIdx.x;
    if (e >= E) return;
    int a = u[e], b = v[e];
    int p = rp_g[b] + atomicAdd(&cnt_g[b], 1);
    col_g[p] = a;
    if (a != b) {
        int p1 = rp_m[b] + atomicAdd(&cnt_m[b], 1);
        col_m[p1] = a;
        int p2 = rp_m[a] + atomicAdd(&cnt_m[a], 1);
        col_m[p2] = b;
    }
}

// ---------------------------------------------------------------------------
// Casts. x -> bf16 (vectorized).
__global__ __launch_bounds__(256) void cast_x_kernel(const float* __restrict__ x,
                                                     ushort* __restrict__ xb,
                                                     int total4) {
    int i = blockIdx.x * 256 + threadIdx.x;
    if (i >= total4) return;
    float4 vv = ((const float4*)x)[i];
    ushort4 o;
    o.x = f2bf(vv.x); o.y = f2bf(vv.y); o.z = f2bf(vv.z); o.w = f2bf(vv.w);
    ((ushort4*)xb)[i] = o;
}

// W[K=256][NOUT] f32 -> Wt[NOUT][256] bf16, with 16B-chunk XOR-swizzle per row:
// physical chunk p of row c holds logical chunk (p ^ (c&7)).
__global__ __launch_bounds__(256) void cast_wt_kernel(const float* __restrict__ W,
                                                      ushort* __restrict__ Wt,
                                                      int NOUT) {
    int idx = blockIdx.x * 256 + threadIdx.x;
    if (idx >= NOUT * 256) return;
    int c = idx >> 8;
    int t = idx & 255;
    int p = t >> 3, j = t & 7;
    int k = ((p ^ (c & 7)) << 3) | j;
    Wt[idx] = f2bf(W[k * NOUT + c]);
}

// ---------------------------------------------------------------------------
// bf16 MFMA GEMM. C[M x NTOT] = rowscale[row] * (A[M x 256] @ W + bias).
// A: bf16 row-major. Bt: bf16 [NTOT][256] transposed weights, chunk-swizzled.
// Tile: 128 rows x TN cols, 256 threads (4 waves).
//   TN=128: waves 2x2, each 64x64 (FM=4). TN=64: waves 4x1, each 32x64 (FM=2).
// B-panel staged to LDS once via global_load_lds (linear copy; swizzle is
// pre-applied in global memory -> conflict-free ds_read_b128 b-fragments).
// A-fragments loaded global->register (16 cache lines per wave-load).
template <int TN, bool OUT_BF16, bool ADD_BIAS>
__global__ __launch_bounds__(256) void mfma_gemm_kernel(
    const ushort* __restrict__ A, const ushort* __restrict__ Bt,
    const float* __restrict__ bias, const float* __restrict__ rowscale,
    void* __restrict__ C, int M, int NTOT) {
    constexpr int BM = 128;
    constexpr int FM = (TN == 128) ? 4 : 2;
    constexpr int FN = 4;
    __shared__ __align__(16) ushort Bs[TN * 256];
    const int tid = threadIdx.x;
    const int w = tid >> 6;
    const int lane = tid & 63;
    const int row0 = blockIdx.x * BM;
    const int col0 = blockIdx.y * TN;
    const int wrow = (TN == 128) ? ((w >> 1) * 64) : (w * 32);
    const int wcol = (TN == 128) ? ((w & 1) * 64) : 0;

    {   // stage B panel (TN*512 bytes), 4KB per iteration (4 wave-issues)
        const char* gB = (const char*)(Bt + (size_t)col0 * 256);
        char* lB = (char*)Bs;
#pragma unroll
        for (int i = 0; i < TN / 8; ++i) {
            gload16(gB + (size_t)(i * 256 + tid) * 16, lB + (i * 256 + w * 64) * 16);
        }
    }
    __syncthreads();

    f32x4 acc[FM][FN];
#pragma unroll
    for (int m = 0; m < FM; ++m)
#pragma unroll
        for (int n = 0; n < FN; ++n) acc[m][n] = {0.f, 0.f, 0.f, 0.f};

    const int g = lane >> 4;
    const int r15 = lane & 15;
    const ushort* arow[FM];
#pragma unroll
    for (int m = 0; m < FM; ++m) {
        int r = row0 + wrow + m * 16 + r15;
        r = (r < M) ? r : (M - 1);
        arow[m] = A + (size_t)r * 256 + g * 8;
    }

#pragma unroll
    for (int ks = 0; ks < 8; ++ks) {
        short8 a[FM], b[FN];
#pragma unroll
        for (int m = 0; m < FM; ++m)
            a[m] = *(const short8*)(arow[m] + ks * 32);
#pragma unroll
        for (int n = 0; n < FN; ++n) {
            int cc = wcol + n * 16 + r15;
            int chunk = (ks * 4 + g) ^ (cc & 7);
            b[n] = *(const short8*)((const char*)Bs + cc * 512 + chunk * 16);
        }
#pragma unroll
        for (int m = 0; m < FM; ++m)
#pragma unroll
            for (int n = 0; n < FN; ++n)
                acc[m][n] = __builtin_amdgcn_mfma_f32_16x16x32_bf16(a[m], b[n], acc[m][n], 0, 0, 0);
    }

#pragma unroll
    for (int m = 0; m < FM; ++m) {
        int rbase = row0 + wrow + m * 16 + g * 4;
#pragma unroll
        for (int j = 0; j < 4; ++j) {
            int grow = rbase + j;
            if (grow >= M) continue;
            float rs = rowscale[grow];
#pragma unroll
            for (int n = 0; n < FN; ++n) {
                int gcol = col0 + wcol + n * 16 + r15;
                float vv = acc[m][n][j];
                if (ADD_BIAS) vv += bias[gcol];
                vv *= rs;
                if (OUT_BF16)
                    ((ushort*)C)[(size_t)grow * NTOT + gcol] = f2bf(vv);
                else
                    ((float*)C)[(size_t)grow * NTOT + gcol] = vv;
            }
        }
    }
}

// ---------------------------------------------------------------------------
// GCN aggregation gather (bf16 rows, f32 accum). h' is pre-scaled by dis:
// out[i] = act( dis[i] * (h'[i] + sum_{u in N(i)} h'[u]) + bias )
template <bool RELU>
__global__ __launch_bounds__(256) void conv_gather_bf16(const ushort* __restrict__ h,
                                                        const float* __restrict__ dis,
                                                        const float* __restrict__ bias,
                                                        const int* __restrict__ rp,
                                                        const int* __restrict__ col,
                                                        ushort* __restrict__ out,
                                                        int N) {
    int wid = (blockIdx.x * blockDim.x + threadIdx.x) >> 6;
    int lane = threadIdx.x & 63;
    if (wid >= N) return;
    const ushort4* h4 = (const ushort4*)h;
    ushort4 sv = h4[(size_t)wid * 64 + lane];
    float a0 = b2f(sv.x), a1 = b2f(sv.y), a2 = b2f(sv.z), a3 = b2f(sv.w);
    int e0 = rp[wid], e1 = rp[wid + 1];
    for (int e = e0; e < e1; ++e) {
        int s = col[e];
        ushort4 nv = h4[(size_t)s * 64 + lane];
        a0 += b2f(nv.x); a1 += b2f(nv.y); a2 += b2f(nv.z); a3 += b2f(nv.w);
    }
    float di = dis[wid];
    float4 bv = ((const float4*)bias)[lane];
    float o0 = di * a0 + bv.x;
    float o1 = di * a1 + bv.y;
    float o2 = di * a2 + bv.z;
    float o3 = di * a3 + bv.w;
    if (RELU) {
        o0 = fmaxf(o0, 0.f); o1 = fmaxf(o1, 0.f);
        o2 = fmaxf(o2, 0.f); o3 = fmaxf(o3, 0.f);
    }
    ushort4 ov;
    ov.x = f2bf(o0); ov.y = f2bf(o1); ov.z = f2bf(o2); ov.w = f2bf(o3);
    ((ushort4*)out)[(size_t)wid * 64 + lane] = ov;
}

// Message-passing gather (f32, D=64): out[i] = dis[i]^POW * sum in[s]
template <int POW>
__global__ __launch_bounds__(256) void mp_gather_kernel(const float* __restrict__ in,
                                                        const float* __restrict__ dis,
                                                        const int* __restrict__ rp,
                                                        const int* __restrict__ col,
                                                        float* __restrict__ out,
                                                        int N) {
    int wid = (blockIdx.x * blockDim.x + threadIdx.x) >> 6;
    int lane = threadIdx.x & 63;
    if (wid >= N) return;
    float acc = 0.0f;
    int e0 = rp[wid], e1 = rp[wid + 1];
    for (int e = e0; e < e1; ++e) {
        int s = col[e];
        acc += in[(size_t)s * DOUT + lane];
    }
    float d = dis[wid];
    float sc = (POW == 2) ? d * d : d;
    out[(size_t)wid * DOUT + lane] = sc * acc;
}

// ---------------------------------------------------------------------------
// Loss: wave per triplet row (wave-stride), 5 butterfly reductions.
__global__ __launch_bounds__(256) void loss_kernel(const float* __restrict__ emb,
                                                   const int* __restrict__ batch,
                                                   float* __restrict__ out,
                                                   int B, float invB) {
    const int nwaves = gridDim.x * 4;
    const int wid = blockIdx.x * 4 + (threadIdx.x >> 6);
    const int lane = threadIdx.x & 63;
    float lsum = 0.0f;
    for (int r = wid; r < B; r += nwaves) {
        int a = batch[r * 3 + 0];
        int p = batch[r * 3 + 1];
        int ng = batch[r * 3 + 2];
        float va = emb[(size_t)a * DOUT + lane];
        float vp = emb[(size_t)p * DOUT + lane];
        float vn = emb[(size_t)ng * DOUT + lane];
        float aa = va * va, pp = vp * vp, nn = vn * vn;
        float ap = va * vp, an = va * vn;
#pragma unroll
        for (int off = 32; off > 0; off >>= 1) {
            aa += __shfl_xor(aa, off);
            pp += __shfl_xor(pp, off);
            nn += __shfl_xor(nn, off);
            ap += __shfl_xor(ap, off);
            an += __shfl_xor(an, off);
        }
        if (lane == 0) {
            float na = fmaxf(sqrtf(aa), 1e-8f);
            float npp = fmaxf(sqrtf(pp), 1e-8f);
            float nnn = fmaxf(sqrtf(nn), 1e-8f);
            float cx = ap / (na * npp);
            float cy = an / (na * nnn);
            lsum += log1pf(expf((cy - cx) * 5.0f));  // 1/TEMP = 5
        }
    }
    __shared__ float part[4];
    if (lane == 0) part[threadIdx.x >> 6] = lsum;
    __syncthreads();
    if (threadIdx.x == 0)
        atomicAdd(out, (part[0] + part[1] + part[2] + part[3]) * invB);
}

// ---------------------------------------------------------------------------
extern "C" void kernel_launch(void* const* d_in, const int* in_sizes, int n_in,
                              void* d_out, int out_size, void* d_ws, size_t ws_size,
                              hipStream_t stream) {
    const float* x   = (const float*)d_in[0];
    const int* ei    = (const int*)d_in[1];
    const int* batch = (const int*)d_in[2];
    const float* W1  = (const float*)d_in[3];
    const float* b1  = (const float*)d_in[4];
    const float* W2  = (const float*)d_in[5];
    const float* b2  = (const float*)d_in[6];
    const float* Wp  = (const float*)d_in[7];
    const float* bp  = (const float*)d_in[8];
    const int N = in_sizes[0] / DIN;
    const int E = in_sizes[1] / 2;
    const int B = in_sizes[2] / 3;
    const int* u = ei;
    const int* v = ei + E;

    // --- workspace layout (~169 MB) ---
    ushort* xb   = (ushort*)d_ws;            // N*256 bf16 (reused as emb0/emb1)
    ushort* hb   = xb + (size_t)N * 256;     // N*256 bf16
    ushort* aggb = hb + (size_t)N * 256;     // N*256 bf16
    ushort* w1t  = aggb + (size_t)N * 256;   // 256*256
    ushort* w2t  = w1t + 256 * 256;          // 256*256
    ushort* wpt  = w2t + 256 * 256;          // 64*256
    float* dis_g = (float*)(wpt + 64 * 256); // N
    float* dis_m = dis_g + N;                // N
    int* rp_g  = (int*)(dis_m + N);          // N+1
    int* rp_m  = rp_g + (N + 1);             // N+1
    int* cnt_g = rp_m + (N + 1);             // N
    int* cnt_m = cnt_g + N;                  // N
    int* col_g = cnt_m + N;                  // E
    int* col_m = col_g + E;                  // 2E
    int* bsum_g = col_m + 2 * (size_t)E;
    const int nb = (N + 255) / 256;
    int* bsum_m = bsum_g + nb;
    float* emb0 = (float*)xb;                // N*64 (xb dead after GEMM1)
    float* emb1 = emb0 + (size_t)N * DOUT;   // N*64

    const int eb = (E + 255) / 256;
    const int nwb = (N + 3) / 4;
    const int gmx = (N + 127) / 128;

    // --- degrees, normalizers, CSR build ---
    hipMemsetAsync(cnt_g, 0, (size_t)N * sizeof(int), stream);
    hipMemsetAsync(cnt_m, 0, (size_t)N * sizeof(int), stream);
    deg_kernel<<<eb, 256, 0, stream>>>(u, v, cnt_g, cnt_m, E);
    dis_kernel<<<(N + 255) / 256, 256, 0, stream>>>(cnt_g, cnt_m, dis_g, dis_m, N);
    scan_reduce_kernel<<<nb, 256, 0, stream>>>(cnt_g, cnt_m, bsum_g, bsum_m, N);
    scan_bsum_kernel<<<1, 64, 0, stream>>>(bsum_g, bsum_m, nb);
    scan_final_kernel<<<nb, 256, 0, stream>>>(cnt_g, cnt_m, bsum_g, bsum_m, rp_g, rp_m, N);
    hipMemsetAsync(cnt_g, 0, (size_t)N * sizeof(int), stream);
    hipMemsetAsync(cnt_m, 0, (size_t)N * sizeof(int), stream);
    fill_kernel<<<eb, 256, 0, stream>>>(u, v, rp_g, rp_m, cnt_g, cnt_m, col_g, col_m, E);

    // --- casts ---
    cast_x_kernel<<<(N * 64 + 255) / 256, 256, 0, stream>>>(x, xb, N * 64);
    cast_wt_kernel<<<(256 * 256 + 255) / 256, 256, 0, stream>>>(W1, w1t, 256);
    cast_wt_kernel<<<(256 * 256 + 255) / 256, 256, 0, stream>>>(W2, w2t, 256);
    cast_wt_kernel<<<(64 * 256 + 255) / 256, 256, 0, stream>>>(Wp, wpt, 64);

    // --- conv1: h' = dis_g * (xb @ W1); agg = relu(gather(h') + b1) ---
    mfma_gemm_kernel<128, true, false><<<dim3(gmx, 2), 256, 0, stream>>>(
        xb, w1t, nullptr, dis_g, hb, N, HID);
    conv_gather_bf16<true><<<nwb, 256, 0, stream>>>(hb, dis_g, b1, rp_g, col_g, aggb, N);

    // --- conv2: h' = dis_g * (agg @ W2); agg = gather(h') + b2 ---
    mfma_gemm_kernel<128, true, false><<<dim3(gmx, 2), 256, 0, stream>>>(
        aggb, w2t, nullptr, dis_g, hb, N, HID);
    conv_gather_bf16<false><<<nwb, 256, 0, stream>>>(hb, dis_g, b2, rp_g, col_g, aggb, N);

    // --- projection: emb0 = dis_m * (agg @ Wp + bp) ---
    mfma_gemm_kernel<64, false, true><<<dim3(gmx, 1), 256, 0, stream>>>(
        aggb, wpt, bp, dis_m, emb0, N, DOUT);

    // --- 2-hop MP: out = D A D^2 A (D emb); D-scales folded into epilogues ---
    mp_gather_kernel<2><<<nwb, 256, 0, stream>>>(emb0, dis_m, rp_m, col_m, emb1, N);
    mp_gather_kernel<1><<<nwb, 256, 0, stream>>>(emb1, dis_m, rp_m, col_m, emb0, N);

    // --- loss ---
    hipMemsetAsync(d_out, 0, sizeof(float), stream);
    loss_kernel<<<1024, 256, 0, stream>>>(emb0, batch, (float*)d_out, B, 1.0f / (float)B);
}

// Round 4
// 992.723 us; speedup vs baseline: 6.9767x; 1.0643x over previous
//
#include <hip/hip_runtime.h>
#include <hip/hip_bf16.h>

#define DIN 256
#define HID 256
#define DOUT 64
#define NPART 8
#define BPP 128  // blocks per partition for deg/fill

typedef short short8 __attribute__((ext_vector_type(8)));
typedef float f32x4 __attribute__((ext_vector_type(4)));

__device__ __forceinline__ float b2f(ushort u) {
    unsigned int x = ((unsigned int)u) << 16;
    return __builtin_bit_cast(float, x);
}
__device__ __forceinline__ ushort f2bf(float f) {
    unsigned int u = __builtin_bit_cast(unsigned int, f);
    unsigned int r = (u + 0x7FFFu + ((u >> 16) & 1u)) >> 16;
    return (ushort)r;
}
__device__ __forceinline__ void gload16(const void* g, void* l) {
    __builtin_amdgcn_global_load_lds(
        (const __attribute__((address_space(1))) unsigned int*)g,
        (__attribute__((address_space(3))) unsigned int*)l, 16, 0, 0);
}

// ---------------------------------------------------------------------------
// XCD-partitioned degree counting. Block b owns node range [part*pdiv,
// (part+1)*pdiv) with part = b & 7 -> under round-robin dispatch each
// partition's cnt/col cache lines are written from a single XCD's L2.
__global__ __launch_bounds__(256) void deg_kernel(const int* __restrict__ u,
                                                  const int* __restrict__ v,
                                                  int* __restrict__ cnt_g,
                                                  int* __restrict__ cnt_m,
                                                  int E, unsigned pdiv) {
    const int part = blockIdx.x & (NPART - 1);
    const int stride = BPP * 256;
    for (int e = (blockIdx.x >> 3) * 256 + threadIdx.x; e < E; e += stride) {
        int a = u[e], b = v[e];
        unsigned pb = (unsigned)b / pdiv;
        unsigned pa = (unsigned)a / pdiv;
        if (pb == (unsigned)part) atomicAdd(&cnt_g[b], 1);
        if (a != b) {
            if (pb == (unsigned)part) atomicAdd(&cnt_m[b], 1);
            if (pa == (unsigned)part) atomicAdd(&cnt_m[a], 1);
        }
    }
}

__global__ __launch_bounds__(256) void dis_kernel(const int* __restrict__ cnt_g,
                                                  const int* __restrict__ cnt_m,
                                                  float* __restrict__ dis_g,
                                                  float* __restrict__ dis_m,
                                                  int N) {
    int i = blockIdx.x * blockDim.x + threadIdx.x;
    if (i >= N) return;
    dis_g[i] = rsqrtf((float)cnt_g[i] + 1.0f);
    int d = cnt_m[i];
    dis_m[i] = (d > 0) ? rsqrtf((float)d) : 0.0f;
}

// ---------------------------------------------------------------------------
// 3-phase exclusive scan for two int arrays at once.
__global__ __launch_bounds__(256) void scan_reduce_kernel(const int* __restrict__ a,
                                                          const int* __restrict__ b,
                                                          int* __restrict__ bsa,
                                                          int* __restrict__ bsb,
                                                          int N) {
    __shared__ int sa[256], sb[256];
    int i = blockIdx.x * 256 + threadIdx.x;
    sa[threadIdx.x] = (i < N) ? a[i] : 0;
    sb[threadIdx.x] = (i < N) ? b[i] : 0;
    __syncthreads();
    for (int s = 128; s > 0; s >>= 1) {
        if (threadIdx.x < s) {
            sa[threadIdx.x] += sa[threadIdx.x + s];
            sb[threadIdx.x] += sb[threadIdx.x + s];
        }
        __syncthreads();
    }
    if (threadIdx.x == 0) { bsa[blockIdx.x] = sa[0]; bsb[blockIdx.x] = sb[0]; }
}

__global__ void scan_bsum_kernel(int* __restrict__ bsa, int* __restrict__ bsb, int nb) {
    if (threadIdx.x == 0) {
        int acc = 0;
        for (int i = 0; i < nb; ++i) { int t = bsa[i]; bsa[i] = acc; acc += t; }
    }
    if (threadIdx.x == 1) {
        int acc = 0;
        for (int i = 0; i < nb; ++i) { int t = bsb[i]; bsb[i] = acc; acc += t; }
    }
}

__global__ __launch_bounds__(256) void scan_final_kernel(const int* __restrict__ a,
                                                         const int* __restrict__ b,
                                                         const int* __restrict__ bsa,
                                                         const int* __restrict__ bsb,
                                                         int* __restrict__ rpa,
                                                         int* __restrict__ rpb,
                                                         int N) {
    __shared__ int sa[256], sb[256];
    int i = blockIdx.x * 256 + threadIdx.x;
    sa[threadIdx.x] = (i < N) ? a[i] : 0;
    sb[threadIdx.x] = (i < N) ? b[i] : 0;
    __syncthreads();
    for (int off = 1; off < 256; off <<= 1) {
        int ta = (threadIdx.x >= off) ? sa[threadIdx.x - off] : 0;
        int tb = (threadIdx.x >= off) ? sb[threadIdx.x - off] : 0;
        __syncthreads();
        sa[threadIdx.x] += ta;
        sb[threadIdx.x] += tb;
        __syncthreads();
    }
    if (i < N) {
        rpa[i + 1] = bsa[blockIdx.x] + sa[threadIdx.x];
        rpb[i + 1] = bsb[blockIdx.x] + sb[threadIdx.x];
    }
    if (i == 0) { rpa[0] = 0; rpb[0] = 0; }
}

// ---------------------------------------------------------------------------
// XCD-partitioned CSR fill (same partition scheme as deg_kernel).
__global__ __launch_bounds__(256) void fill_kernel(const int* __restrict__ u,
                                                   const int* __restrict__ v,
                                                   const int* __restrict__ rp_g,
                                                   const int* __restrict__ rp_m,
                                                   int* __restrict__ cnt_g,
                                                   int* __restrict__ cnt_m,
                                                   int* __restrict__ col_g,
                                                   int* __restrict__ col_m,
                                                   int E, unsigned pdiv) {
    const int part = blockIdx.x & (NPART - 1);
    const int stride = BPP * 256;
    for (int e = (blockIdx.x >> 3) * 256 + threadIdx.x; e < E; e += stride) {
        int a = u[e], b = v[e];
        unsigned pb = (unsigned)b / pdiv;
        unsigned pa = (unsigned)a / pdiv;
        if (pb == (unsigned)part) {
            int p = rp_g[b] + atomicAdd(&cnt_g[b], 1);
            col_g[p] = a;
        }
        if (a != b) {
            if (pb == (unsigned)part) {
                int p1 = rp_m[b] + atomicAdd(&cnt_m[b], 1);
                col_m[p1] = a;
            }
            if (pa == (unsigned)part) {
                int p2 = rp_m[a] + atomicAdd(&cnt_m[a], 1);
                col_m[p2] = b;
            }
        }
    }
}

// ---------------------------------------------------------------------------
// Casts. x -> bf16 (vectorized).
__global__ __launch_bounds__(256) void cast_x_kernel(const float* __restrict__ x,
                                                     ushort* __restrict__ xb,
                                                     int total4) {
    int i = blockIdx.x * 256 + threadIdx.x;
    if (i >= total4) return;
    float4 vv = ((const float4*)x)[i];
    ushort4 o;
    o.x = f2bf(vv.x); o.y = f2bf(vv.y); o.z = f2bf(vv.z); o.w = f2bf(vv.w);
    ((ushort4*)xb)[i] = o;
}

// W[K=256][NOUT] f32 -> Wt[NOUT][256] bf16, with 16B-chunk XOR-swizzle per row.
__global__ __launch_bounds__(256) void cast_wt_kernel(const float* __restrict__ W,
                                                      ushort* __restrict__ Wt,
                                                      int NOUT) {
    int idx = blockIdx.x * 256 + threadIdx.x;
    if (idx >= NOUT * 256) return;
    int c = idx >> 8;
    int t = idx & 255;
    int p = t >> 3, j = t & 7;
    int k = ((p ^ (c & 7)) << 3) | j;
    Wt[idx] = f2bf(W[k * NOUT + c]);
}

// ---------------------------------------------------------------------------
// bf16 MFMA GEMM. C[M x NTOT] = rowscale[row] * (A[M x 256] @ W + bias).
template <int TN, bool OUT_BF16, bool ADD_BIAS>
__global__ __launch_bounds__(256) void mfma_gemm_kernel(
    const ushort* __restrict__ A, const ushort* __restrict__ Bt,
    const float* __restrict__ bias, const float* __restrict__ rowscale,
    void* __restrict__ C, int M, int NTOT) {
    constexpr int BM = 128;
    constexpr int FM = (TN == 128) ? 4 : 2;
    constexpr int FN = 4;
    __shared__ __align__(16) ushort Bs[TN * 256];
    const int tid = threadIdx.x;
    const int w = tid >> 6;
    const int lane = tid & 63;
    const int row0 = blockIdx.x * BM;
    const int col0 = blockIdx.y * TN;
    const int wrow = (TN == 128) ? ((w >> 1) * 64) : (w * 32);
    const int wcol = (TN == 128) ? ((w & 1) * 64) : 0;

    {   // stage B panel (TN*512 bytes)
        const char* gB = (const char*)(Bt + (size_t)col0 * 256);
        char* lB = (char*)Bs;
#pragma unroll
        for (int i = 0; i < TN / 8; ++i) {
            gload16(gB + (size_t)(i * 256 + tid) * 16, lB + (i * 256 + w * 64) * 16);
        }
    }
    __syncthreads();

    f32x4 acc[FM][FN];
#pragma unroll
    for (int m = 0; m < FM; ++m)
#pragma unroll
        for (int n = 0; n < FN; ++n) acc[m][n] = {0.f, 0.f, 0.f, 0.f};

    const int g = lane >> 4;
    const int r15 = lane & 15;
    const ushort* arow[FM];
#pragma unroll
    for (int m = 0; m < FM; ++m) {
        int r = row0 + wrow + m * 16 + r15;
        r = (r < M) ? r : (M - 1);
        arow[m] = A + (size_t)r * 256 + g * 8;
    }

#pragma unroll
    for (int ks = 0; ks < 8; ++ks) {
        short8 a[FM], b[FN];
#pragma unroll
        for (int m = 0; m < FM; ++m)
            a[m] = *(const short8*)(arow[m] + ks * 32);
#pragma unroll
        for (int n = 0; n < FN; ++n) {
            int cc = wcol + n * 16 + r15;
            int chunk = (ks * 4 + g) ^ (cc & 7);
            b[n] = *(const short8*)((const char*)Bs + cc * 512 + chunk * 16);
        }
#pragma unroll
        for (int m = 0; m < FM; ++m)
#pragma unroll
            for (int n = 0; n < FN; ++n)
                acc[m][n] = __builtin_amdgcn_mfma_f32_16x16x32_bf16(a[m], b[n], acc[m][n], 0, 0, 0);
    }

#pragma unroll
    for (int m = 0; m < FM; ++m) {
        int rbase = row0 + wrow + m * 16 + g * 4;
#pragma unroll
        for (int j = 0; j < 4; ++j) {
            int grow = rbase + j;
            if (grow >= M) continue;
            float rs = rowscale[grow];
#pragma unroll
            for (int n = 0; n < FN; ++n) {
                int gcol = col0 + wcol + n * 16 + r15;
                float vv = acc[m][n][j];
                if (ADD_BIAS) vv += bias[gcol];
                vv *= rs;
                if (OUT_BF16)
                    ((ushort*)C)[(size_t)grow * NTOT + gcol] = f2bf(vv);
                else
                    ((float*)C)[(size_t)grow * NTOT + gcol] = vv;
            }
        }
    }
}

// ---------------------------------------------------------------------------
// GCN aggregation gather (bf16 rows, f32 accum). h' is pre-scaled by dis:
// out[i] = act( dis[i] * (h'[i] + sum_{u in N(i)} h'[u]) + bias )
template <bool RELU>
__global__ __launch_bounds__(256) void conv_gather_bf16(const ushort* __restrict__ h,
                                                        const float* __restrict__ dis,
                                                        const float* __restrict__ bias,
                                                        const int* __restrict__ rp,
                                                        const int* __restrict__ col,
                                                        ushort* __restrict__ out,
                                                        int N) {
    int wid = (blockIdx.x * blockDim.x + threadIdx.x) >> 6;
    int lane = threadIdx.x & 63;
    if (wid >= N) return;
    const ushort4* h4 = (const ushort4*)h;
    ushort4 sv = h4[(size_t)wid * 64 + lane];
    float a0 = b2f(sv.x), a1 = b2f(sv.y), a2 = b2f(sv.z), a3 = b2f(sv.w);
    int e0 = rp[wid], e1 = rp[wid + 1];
    for (int e = e0; e < e1; ++e) {
        int s = col[e];
        ushort4 nv = h4[(size_t)s * 64 + lane];
        a0 += b2f(nv.x); a1 += b2f(nv.y); a2 += b2f(nv.z); a3 += b2f(nv.w);
    }
    float di = dis[wid];
    float4 bv = ((const float4*)bias)[lane];
    float o0 = di * a0 + bv.x;
    float o1 = di * a1 + bv.y;
    float o2 = di * a2 + bv.z;
    float o3 = di * a3 + bv.w;
    if (RELU) {
        o0 = fmaxf(o0, 0.f); o1 = fmaxf(o1, 0.f);
        o2 = fmaxf(o2, 0.f); o3 = fmaxf(o3, 0.f);
    }
    ushort4 ov;
    ov.x = f2bf(o0); ov.y = f2bf(o1); ov.z = f2bf(o2); ov.w = f2bf(o3);
    ((ushort4*)out)[(size_t)wid * 64 + lane] = ov;
}

// Message-passing gather (f32, D=64): out[i] = dis[i]^POW * sum in[s]
template <int POW>
__global__ __launch_bounds__(256) void mp_gather_kernel(const float* __restrict__ in,
                                                        const float* __restrict__ dis,
                                                        const int* __restrict__ rp,
                                                        const int* __restrict__ col,
                                                        float* __restrict__ out,
                                                        int N) {
    int wid = (blockIdx.x * blockDim.x + threadIdx.x) >> 6;
    int lane = threadIdx.x & 63;
    if (wid >= N) return;
    float acc = 0.0f;
    int e0 = rp[wid], e1 = rp[wid + 1];
    for (int e = e0; e < e1; ++e) {
        int s = col[e];
        acc += in[(size_t)s * DOUT + lane];
    }
    float d = dis[wid];
    float sc = (POW == 2) ? d * d : d;
    out[(size_t)wid * DOUT + lane] = sc * acc;
}

// ---------------------------------------------------------------------------
// Loss: wave per triplet row (wave-stride), 5 butterfly reductions.
__global__ __launch_bounds__(256) void loss_kernel(const float* __restrict__ emb,
                                                   const int* __restrict__ batch,
                                                   float* __restrict__ out,
                                                   int B, float invB) {
    const int nwaves = gridDim.x * 4;
    const int wid = blockIdx.x * 4 + (threadIdx.x >> 6);
    const int lane = threadIdx.x & 63;
    float lsum = 0.0f;
    for (int r = wid; r < B; r += nwaves) {
        int a = batch[r * 3 + 0];
        int p = batch[r * 3 + 1];
        int ng = batch[r * 3 + 2];
        float va = emb[(size_t)a * DOUT + lane];
        float vp = emb[(size_t)p * DOUT + lane];
        float vn = emb[(size_t)ng * DOUT + lane];
        float aa = va * va, pp = vp * vp, nn = vn * vn;
        float ap = va * vp, an = va * vn;
#pragma unroll
        for (int off = 32; off > 0; off >>= 1) {
            aa += __shfl_xor(aa, off);
            pp += __shfl_xor(pp, off);
            nn += __shfl_xor(nn, off);
            ap += __shfl_xor(ap, off);
            an += __shfl_xor(an, off);
        }
        if (lane == 0) {
            float na = fmaxf(sqrtf(aa), 1e-8f);
            float npp = fmaxf(sqrtf(pp), 1e-8f);
            float nnn = fmaxf(sqrtf(nn), 1e-8f);
            float cx = ap / (na * npp);
            float cy = an / (na * nnn);
            lsum += log1pf(expf((cy - cx) * 5.0f));  // 1/TEMP = 5
        }
    }
    __shared__ float part[4];
    if (lane == 0) part[threadIdx.x >> 6] = lsum;
    __syncthreads();
    if (threadIdx.x == 0)
        atomicAdd(out, (part[0] + part[1] + part[2] + part[3]) * invB);
}

// ---------------------------------------------------------------------------
extern "C" void kernel_launch(void* const* d_in, const int* in_sizes, int n_in,
                              void* d_out, int out_size, void* d_ws, size_t ws_size,
                              hipStream_t stream) {
    const float* x   = (const float*)d_in[0];
    const int* ei    = (const int*)d_in[1];
    const int* batch = (const int*)d_in[2];
    const float* W1  = (const float*)d_in[3];
    const float* b1  = (const float*)d_in[4];
    const float* W2  = (const float*)d_in[5];
    const float* b2  = (const float*)d_in[6];
    const float* Wp  = (const float*)d_in[7];
    const float* bp  = (const float*)d_in[8];
    const int N = in_sizes[0] / DIN;
    const int E = in_sizes[1] / 2;
    const int B = in_sizes[2] / 3;
    const int* u = ei;
    const int* v = ei + E;
    const unsigned pdiv = (unsigned)((N + NPART - 1) / NPART);

    // --- workspace layout ---
    ushort* xb   = (ushort*)d_ws;            // N*256 bf16 (reused as emb0/emb1)
    ushort* hb   = xb + (size_t)N * 256;     // N*256 bf16
    ushort* aggb = hb + (size_t)N * 256;     // N*256 bf16
    ushort* w1t  = aggb + (size_t)N * 256;   // 256*256
    ushort* w2t  = w1t + 256 * 256;          // 256*256
    ushort* wpt  = w2t + 256 * 256;          // 64*256
    float* dis_g = (float*)(wpt + 64 * 256); // N
    float* dis_m = dis_g + N;                // N
    int* rp_g  = (int*)(dis_m + N);          // N+1
    int* rp_m  = rp_g + (N + 1);             // N+1
    int* cnt_g = rp_m + (N + 1);             // N
    int* cnt_m = cnt_g + N;                  // N
    int* col_g = cnt_m + N;                  // E
    int* col_m = col_g + E;                  // 2E
    int* bsum_g = col_m + 2 * (size_t)E;
    const int nb = (N + 255) / 256;
    int* bsum_m = bsum_g + nb;
    float* emb0 = (float*)xb;                // N*64 (xb dead after GEMM1)
    float* emb1 = emb0 + (size_t)N * DOUT;   // N*64

    const int nwb = (N + 3) / 4;
    const int gmx = (N + 127) / 128;

    // --- degrees, normalizers, CSR build (XCD-partitioned scatter) ---
    hipMemsetAsync(cnt_g, 0, 2 * (size_t)N * sizeof(int), stream);  // cnt_g+cnt_m
    deg_kernel<<<NPART * BPP, 256, 0, stream>>>(u, v, cnt_g, cnt_m, E, pdiv);
    dis_kernel<<<(N + 255) / 256, 256, 0, stream>>>(cnt_g, cnt_m, dis_g, dis_m, N);
    scan_reduce_kernel<<<nb, 256, 0, stream>>>(cnt_g, cnt_m, bsum_g, bsum_m, N);
    scan_bsum_kernel<<<1, 64, 0, stream>>>(bsum_g, bsum_m, nb);
    scan_final_kernel<<<nb, 256, 0, stream>>>(cnt_g, cnt_m, bsum_g, bsum_m, rp_g, rp_m, N);
    hipMemsetAsync(cnt_g, 0, 2 * (size_t)N * sizeof(int), stream);
    fill_kernel<<<NPART * BPP, 256, 0, stream>>>(u, v, rp_g, rp_m, cnt_g, cnt_m, col_g, col_m, E, pdiv);

    // --- casts ---
    cast_x_kernel<<<(N * 64 + 255) / 256, 256, 0, stream>>>(x, xb, N * 64);
    cast_wt_kernel<<<(256 * 256 + 255) / 256, 256, 0, stream>>>(W1, w1t, 256);
    cast_wt_kernel<<<(256 * 256 + 255) / 256, 256, 0, stream>>>(W2, w2t, 256);
    cast_wt_kernel<<<(64 * 256 + 255) / 256, 256, 0, stream>>>(Wp, wpt, 64);

    // --- conv1: h' = dis_g * (xb @ W1); agg = relu(gather(h') + b1) ---
    mfma_gemm_kernel<128, true, false><<<dim3(gmx, 2), 256, 0, stream>>>(
        xb, w1t, nullptr, dis_g, hb, N, HID);
    conv_gather_bf16<true><<<nwb, 256, 0, stream>>>(hb, dis_g, b1, rp_g, col_g, aggb, N);

    // --- conv2: h' = dis_g * (agg @ W2); agg = gather(h') + b2 ---
    mfma_gemm_kernel<128, true, false><<<dim3(gmx, 2), 256, 0, stream>>>(
        aggb, w2t, nullptr, dis_g, hb, N, HID);
    conv_gather_bf16<false><<<nwb, 256, 0, stream>>>(hb, dis_g, b2, rp_g, col_g, aggb, N);

    // --- projection: emb0 = dis_m * (agg @ Wp + bp) ---
    mfma_gemm_kernel<64, false, true><<<dim3(gmx, 1), 256, 0, stream>>>(
        aggb, wpt, bp, dis_m, emb0, N, DOUT);

    // --- 2-hop MP: out = D A D^2 A (D emb); D-scales folded into epilogues ---
    mp_gather_kernel<2><<<nwb, 256, 0, stream>>>(emb0, dis_m, rp_m, col_m, emb1, N);
    mp_gather_kernel<1><<<nwb, 256, 0, stream>>>(emb1, dis_m, rp_m, col_m, emb0, N);

    // --- loss ---
    hipMemsetAsync(d_out, 0, sizeof(float), stream);
    loss_kernel<<<1024, 256, 0, stream>>>(emb0, batch, (float*)d_out, B, 1.0f / (float)B);
}

// Round 5
// 846.530 us; speedup vs baseline: 8.1816x; 1.1727x over previous
//
#include <hip/hip_runtime.h>
#include <hip/hip_bf16.h>

#define DIN 256
#define HID 256
#define DOUT 64
#define NPART 8
#define BPP 128  // blocks per partition for deg/fill

typedef short short8 __attribute__((ext_vector_type(8)));
typedef float f32x4 __attribute__((ext_vector_type(4)));

__device__ __forceinline__ float b2f(ushort u) {
    unsigned int x = ((unsigned int)u) << 16;
    return __builtin_bit_cast(float, x);
}
__device__ __forceinline__ ushort f2bf(float f) {
    unsigned int u = __builtin_bit_cast(unsigned int, f);
    unsigned int r = (u + 0x7FFFu + ((u >> 16) & 1u)) >> 16;
    return (ushort)r;
}
__device__ __forceinline__ void gload16(const void* g, void* l) {
    __builtin_amdgcn_global_load_lds(
        (const __attribute__((address_space(1))) unsigned int*)g,
        (__attribute__((address_space(3))) unsigned int*)l, 16, 0, 0);
}

// ---------------------------------------------------------------------------
// XCD-partitioned degree counting (see round-4 notes: block b owns node range
// part = b & 7 so each partition's counter lines are written from one XCD).
__global__ __launch_bounds__(256) void deg_kernel(const int* __restrict__ u,
                                                  const int* __restrict__ v,
                                                  int* __restrict__ cnt_g,
                                                  int* __restrict__ cnt_m,
                                                  int E, unsigned pdiv) {
    const int part = blockIdx.x & (NPART - 1);
    const int stride = BPP * 256;
    for (int e = (blockIdx.x >> 3) * 256 + threadIdx.x; e < E; e += stride) {
        int a = u[e], b = v[e];
        unsigned pb = (unsigned)b / pdiv;
        unsigned pa = (unsigned)a / pdiv;
        if (pb == (unsigned)part) atomicAdd(&cnt_g[b], 1);
        if (a != b) {
            if (pb == (unsigned)part) atomicAdd(&cnt_m[b], 1);
            if (pa == (unsigned)part) atomicAdd(&cnt_m[a], 1);
        }
    }
}

__global__ __launch_bounds__(256) void dis_kernel(const int* __restrict__ cnt_g,
                                                  const int* __restrict__ cnt_m,
                                                  float* __restrict__ dis_g,
                                                  float* __restrict__ dis_m,
                                                  int N) {
    int i = blockIdx.x * blockDim.x + threadIdx.x;
    if (i >= N) return;
    dis_g[i] = rsqrtf((float)cnt_g[i] + 1.0f);
    int d = cnt_m[i];
    dis_m[i] = (d > 0) ? rsqrtf((float)d) : 0.0f;
}

// ---------------------------------------------------------------------------
// 3-phase exclusive scan for two int arrays at once.
__global__ __launch_bounds__(256) void scan_reduce_kernel(const int* __restrict__ a,
                                                          const int* __restrict__ b,
                                                          int* __restrict__ bsa,
                                                          int* __restrict__ bsb,
                                                          int N) {
    __shared__ int sa[256], sb[256];
    int i = blockIdx.x * 256 + threadIdx.x;
    sa[threadIdx.x] = (i < N) ? a[i] : 0;
    sb[threadIdx.x] = (i < N) ? b[i] : 0;
    __syncthreads();
    for (int s = 128; s > 0; s >>= 1) {
        if (threadIdx.x < s) {
            sa[threadIdx.x] += sa[threadIdx.x + s];
            sb[threadIdx.x] += sb[threadIdx.x + s];
        }
        __syncthreads();
    }
    if (threadIdx.x == 0) { bsa[blockIdx.x] = sa[0]; bsb[blockIdx.x] = sb[0]; }
}

__global__ void scan_bsum_kernel(int* __restrict__ bsa, int* __restrict__ bsb, int nb) {
    if (threadIdx.x == 0) {
        int acc = 0;
        for (int i = 0; i < nb; ++i) { int t = bsa[i]; bsa[i] = acc; acc += t; }
    }
    if (threadIdx.x == 1) {
        int acc = 0;
        for (int i = 0; i < nb; ++i) { int t = bsb[i]; bsb[i] = acc; acc += t; }
    }
}

__global__ __launch_bounds__(256) void scan_final_kernel(const int* __restrict__ a,
                                                         const int* __restrict__ b,
                                                         const int* __restrict__ bsa,
                                                         const int* __restrict__ bsb,
                                                         int* __restrict__ rpa,
                                                         int* __restrict__ rpb,
                                                         int N) {
    __shared__ int sa[256], sb[256];
    int i = blockIdx.x * 256 + threadIdx.x;
    sa[threadIdx.x] = (i < N) ? a[i] : 0;
    sb[threadIdx.x] = (i < N) ? b[i] : 0;
    __syncthreads();
    for (int off = 1; off < 256; off <<= 1) {
        int ta = (threadIdx.x >= off) ? sa[threadIdx.x - off] : 0;
        int tb = (threadIdx.x >= off) ? sb[threadIdx.x - off] : 0;
        __syncthreads();
        sa[threadIdx.x] += ta;
        sb[threadIdx.x] += tb;
        __syncthreads();
    }
    if (i < N) {
        rpa[i + 1] = bsa[blockIdx.x] + sa[threadIdx.x];
        rpb[i + 1] = bsb[blockIdx.x] + sb[threadIdx.x];
    }
    if (i == 0) { rpa[0] = 0; rpb[0] = 0; }
}

// ---------------------------------------------------------------------------
// XCD-partitioned CSR fill.
__global__ __launch_bounds__(256) void fill_kernel(const int* __restrict__ u,
                                                   const int* __restrict__ v,
                                                   const int* __restrict__ rp_g,
                                                   const int* __restrict__ rp_m,
                                                   int* __restrict__ cnt_g,
                                                   int* __restrict__ cnt_m,
                                                   int* __restrict__ col_g,
                                                   int* __restrict__ col_m,
                                                   int E, unsigned pdiv) {
    const int part = blockIdx.x & (NPART - 1);
    const int stride = BPP * 256;
    for (int e = (blockIdx.x >> 3) * 256 + threadIdx.x; e < E; e += stride) {
        int a = u[e], b = v[e];
        unsigned pb = (unsigned)b / pdiv;
        unsigned pa = (unsigned)a / pdiv;
        if (pb == (unsigned)part) {
            int p = rp_g[b] + atomicAdd(&cnt_g[b], 1);
            col_g[p] = a;
        }
        if (a != b) {
            if (pb == (unsigned)part) {
                int p1 = rp_m[b] + atomicAdd(&cnt_m[b], 1);
                col_m[p1] = a;
            }
            if (pa == (unsigned)part) {
                int p2 = rp_m[a] + atomicAdd(&cnt_m[a], 1);
                col_m[p2] = b;
            }
        }
    }
}

// ---------------------------------------------------------------------------
// W[K=256][NOUT] f32 -> Wt[NOUT][256] bf16, 16B-chunk XOR-swizzle per row.
__global__ __launch_bounds__(256) void cast_wt_kernel(const float* __restrict__ W,
                                                      ushort* __restrict__ Wt,
                                                      int NOUT) {
    int idx = blockIdx.x * 256 + threadIdx.x;
    if (idx >= NOUT * 256) return;
    int c = idx >> 8;
    int t = idx & 255;
    int p = t >> 3, j = t & 7;
    int k = ((p ^ (c & 7)) << 3) | j;
    Wt[idx] = f2bf(W[k * NOUT + c]);
}

// ---------------------------------------------------------------------------
// bf16 MFMA GEMM. C[M x NTOT] = rowscale[row] * (A[M x 256] @ W + bias).
// A_F32: A is f32 and converted to bf16 in-register (fuses the input cast).
template <int TN, bool OUT_BF16, bool ADD_BIAS, bool A_F32>
__global__ __launch_bounds__(256) void mfma_gemm_kernel(
    const void* __restrict__ A, const ushort* __restrict__ Bt,
    const float* __restrict__ bias, const float* __restrict__ rowscale,
    void* __restrict__ C, int M, int NTOT) {
    constexpr int BM = 128;
    constexpr int FM = (TN == 128) ? 4 : 2;
    constexpr int FN = 4;
    __shared__ __align__(16) ushort Bs[TN * 256];
    const int tid = threadIdx.x;
    const int w = tid >> 6;
    const int lane = tid & 63;
    const int row0 = blockIdx.x * BM;
    const int col0 = blockIdx.y * TN;
    const int wrow = (TN == 128) ? ((w >> 1) * 64) : (w * 32);
    const int wcol = (TN == 128) ? ((w & 1) * 64) : 0;

    {   // stage B panel (TN*512 bytes)
        const char* gB = (const char*)(Bt + (size_t)col0 * 256);
        char* lB = (char*)Bs;
#pragma unroll
        for (int i = 0; i < TN / 8; ++i) {
            gload16(gB + (size_t)(i * 256 + tid) * 16, lB + (i * 256 + w * 64) * 16);
        }
    }
    __syncthreads();

    f32x4 acc[FM][FN];
#pragma unroll
    for (int m = 0; m < FM; ++m)
#pragma unroll
        for (int n = 0; n < FN; ++n) acc[m][n] = {0.f, 0.f, 0.f, 0.f};

    const int g = lane >> 4;
    const int r15 = lane & 15;
    const void* arow[FM];
#pragma unroll
    for (int m = 0; m < FM; ++m) {
        int r = row0 + wrow + m * 16 + r15;
        r = (r < M) ? r : (M - 1);
        if (A_F32)
            arow[m] = (const void*)((const float*)A + (size_t)r * 256 + g * 8);
        else
            arow[m] = (const void*)((const ushort*)A + (size_t)r * 256 + g * 8);
    }

#pragma unroll
    for (int ks = 0; ks < 8; ++ks) {
        short8 a[FM], b[FN];
#pragma unroll
        for (int m = 0; m < FM; ++m) {
            if (A_F32) {
                const float* ap = (const float*)arow[m] + ks * 32;
                float4 f0 = *(const float4*)ap;
                float4 f1 = *(const float4*)(ap + 4);
                short8 t;
                t[0] = (short)f2bf(f0.x); t[1] = (short)f2bf(f0.y);
                t[2] = (short)f2bf(f0.z); t[3] = (short)f2bf(f0.w);
                t[4] = (short)f2bf(f1.x); t[5] = (short)f2bf(f1.y);
                t[6] = (short)f2bf(f1.z); t[7] = (short)f2bf(f1.w);
                a[m] = t;
            } else {
                a[m] = *(const short8*)((const ushort*)arow[m] + ks * 32);
            }
        }
#pragma unroll
        for (int n = 0; n < FN; ++n) {
            int cc = wcol + n * 16 + r15;
            int chunk = (ks * 4 + g) ^ (cc & 7);
            b[n] = *(const short8*)((const char*)Bs + cc * 512 + chunk * 16);
        }
#pragma unroll
        for (int m = 0; m < FM; ++m)
#pragma unroll
            for (int n = 0; n < FN; ++n)
                acc[m][n] = __builtin_amdgcn_mfma_f32_16x16x32_bf16(a[m], b[n], acc[m][n], 0, 0, 0);
    }

#pragma unroll
    for (int m = 0; m < FM; ++m) {
        int rbase = row0 + wrow + m * 16 + g * 4;
#pragma unroll
        for (int j = 0; j < 4; ++j) {
            int grow = rbase + j;
            if (grow >= M) continue;
            float rs = rowscale[grow];
#pragma unroll
            for (int n = 0; n < FN; ++n) {
                int gcol = col0 + wcol + n * 16 + r15;
                float vv = acc[m][n][j];
                if (ADD_BIAS) vv += bias[gcol];
                vv *= rs;
                if (OUT_BF16)
                    ((ushort*)C)[(size_t)grow * NTOT + gcol] = f2bf(vv);
                else
                    ((float*)C)[(size_t)grow * NTOT + gcol] = vv;
            }
        }
    }
}

// ---------------------------------------------------------------------------
// GCN aggregation gather (bf16 rows, f32 accum). h' pre-scaled by dis:
// out[i] = act( dis[i] * (h'[i] + sum_{u in N(i)} h'[u]) + bias )
template <bool RELU>
__global__ __launch_bounds__(256) void conv_gather_bf16(const ushort* __restrict__ h,
                                                        const float* __restrict__ dis,
                                                        const float* __restrict__ bias,
                                                        const int* __restrict__ rp,
                                                        const int* __restrict__ col,
                                                        ushort* __restrict__ out,
                                                        int N) {
    int wid = (blockIdx.x * blockDim.x + threadIdx.x) >> 6;
    int lane = threadIdx.x & 63;
    if (wid >= N) return;
    const ushort4* h4 = (const ushort4*)h;
    ushort4 sv = h4[(size_t)wid * 64 + lane];
    float a0 = b2f(sv.x), a1 = b2f(sv.y), a2 = b2f(sv.z), a3 = b2f(sv.w);
    int e0 = rp[wid], e1 = rp[wid + 1];
    for (int e = e0; e < e1; ++e) {
        int s = col[e];
        ushort4 nv = h4[(size_t)s * 64 + lane];
        a0 += b2f(nv.x); a1 += b2f(nv.y); a2 += b2f(nv.z); a3 += b2f(nv.w);
    }
    float di = dis[wid];
    float4 bv = ((const float4*)bias)[lane];
    float o0 = di * a0 + bv.x;
    float o1 = di * a1 + bv.y;
    float o2 = di * a2 + bv.z;
    float o3 = di * a3 + bv.w;
    if (RELU) {
        o0 = fmaxf(o0, 0.f); o1 = fmaxf(o1, 0.f);
        o2 = fmaxf(o2, 0.f); o3 = fmaxf(o3, 0.f);
    }
    ushort4 ov;
    ov.x = f2bf(o0); ov.y = f2bf(o1); ov.z = f2bf(o2); ov.w = f2bf(o3);
    ((ushort4*)out)[(size_t)wid * 64 + lane] = ov;
}

// Message-passing gather, bf16 rows (128 B), f32 accum.
// Wave handles one node; lanes 0-31 process even edges of the list, 32-63 odd.
// Each lane owns dim pair (2*l2, 2*l2+1); halves merged via shfl_xor(32).
template <int POW>
__global__ __launch_bounds__(256) void mp_gather_bf16(const ushort* __restrict__ in,
                                                      const float* __restrict__ dis,
                                                      const int* __restrict__ rp,
                                                      const int* __restrict__ col,
                                                      ushort* __restrict__ out,
                                                      int N) {
    int wid = (blockIdx.x * blockDim.x + threadIdx.x) >> 6;
    int lane = threadIdx.x & 63;
    if (wid >= N) return;
    const int half = lane >> 5;
    const int l2 = lane & 31;
    float a0 = 0.f, a1 = 0.f;
    int e0 = rp[wid], e1 = rp[wid + 1];
    for (int e = e0 + half; e < e1; e += 2) {
        int s = col[e];
        ushort2 nv = *(const ushort2*)(in + (size_t)s * DOUT + l2 * 2);
        a0 += b2f(nv.x);
        a1 += b2f(nv.y);
    }
    a0 += __shfl_xor(a0, 32);
    a1 += __shfl_xor(a1, 32);
    if (half == 0) {
        float d = dis[wid];
        float sc = (POW == 2) ? d * d : d;
        ushort2 ov;
        ov.x = f2bf(sc * a0);
        ov.y = f2bf(sc * a1);
        *(ushort2*)(out + (size_t)wid * DOUT + l2 * 2) = ov;
    }
}

// ---------------------------------------------------------------------------
// Loss: half-wave per triplet (bf16 emb rows, ushort2 per lane = 4 B).
__global__ __launch_bounds__(256) void loss_kernel(const ushort* __restrict__ emb,
                                                   const int* __restrict__ batch,
                                                   float* __restrict__ out,
                                                   int B, float invB) {
    const int nhw = gridDim.x * 8;
    const int hwid = blockIdx.x * 8 + (threadIdx.x >> 5);
    const int l2 = threadIdx.x & 31;
    float lsum = 0.0f;
    for (int r = hwid; r < B; r += nhw) {
        int a = batch[r * 3 + 0];
        int p = batch[r * 3 + 1];
        int ng = batch[r * 3 + 2];
        ushort2 wa = *(const ushort2*)(emb + (size_t)a * DOUT + l2 * 2);
        ushort2 wp = *(const ushort2*)(emb + (size_t)p * DOUT + l2 * 2);
        ushort2 wn = *(const ushort2*)(emb + (size_t)ng * DOUT + l2 * 2);
        float va0 = b2f(wa.x), va1 = b2f(wa.y);
        float vp0 = b2f(wp.x), vp1 = b2f(wp.y);
        float vn0 = b2f(wn.x), vn1 = b2f(wn.y);
        float aa = va0 * va0 + va1 * va1;
        float pp = vp0 * vp0 + vp1 * vp1;
        float nn = vn0 * vn0 + vn1 * vn1;
        float ap = va0 * vp0 + va1 * vp1;
        float an = va0 * vn0 + va1 * vn1;
#pragma unroll
        for (int off = 16; off > 0; off >>= 1) {
            aa += __shfl_xor(aa, off);
            pp += __shfl_xor(pp, off);
            nn += __shfl_xor(nn, off);
            ap += __shfl_xor(ap, off);
            an += __shfl_xor(an, off);
        }
        if (l2 == 0) {
            float na = fmaxf(sqrtf(aa), 1e-8f);
            float npp = fmaxf(sqrtf(pp), 1e-8f);
            float nnn = fmaxf(sqrtf(nn), 1e-8f);
            float cx = ap / (na * npp);
            float cy = an / (na * nnn);
            lsum += log1pf(expf((cy - cx) * 5.0f));  // 1/TEMP = 5
        }
    }
    __shared__ float part[8];
    if (l2 == 0) part[threadIdx.x >> 5] = lsum;
    __syncthreads();
    if (threadIdx.x == 0) {
        float s = 0.f;
#pragma unroll
        for (int i = 0; i < 8; ++i) s += part[i];
        atomicAdd(out, s * invB);
    }
}

// ---------------------------------------------------------------------------
extern "C" void kernel_launch(void* const* d_in, const int* in_sizes, int n_in,
                              void* d_out, int out_size, void* d_ws, size_t ws_size,
                              hipStream_t stream) {
    const float* x   = (const float*)d_in[0];
    const int* ei    = (const int*)d_in[1];
    const int* batch = (const int*)d_in[2];
    const float* W1  = (const float*)d_in[3];
    const float* b1  = (const float*)d_in[4];
    const float* W2  = (const float*)d_in[5];
    const float* b2  = (const float*)d_in[6];
    const float* Wp  = (const float*)d_in[7];
    const float* bp  = (const float*)d_in[8];
    const int N = in_sizes[0] / DIN;
    const int E = in_sizes[1] / 2;
    const int B = in_sizes[2] / 3;
    const int* u = ei;
    const int* v = ei + E;
    const unsigned pdiv = (unsigned)((N + NPART - 1) / NPART);

    // --- workspace layout ---
    ushort* hb   = (ushort*)d_ws;            // N*256 bf16
    ushort* aggb = hb + (size_t)N * 256;     // N*256 bf16
    ushort* embA = aggb + (size_t)N * 256;   // N*64 bf16
    ushort* embB = embA + (size_t)N * DOUT;  // N*64 bf16
    ushort* w1t  = embB + (size_t)N * DOUT;  // 256*256
    ushort* w2t  = w1t + 256 * 256;          // 256*256
    ushort* wpt  = w2t + 256 * 256;          // 64*256
    float* dis_g = (float*)(wpt + 64 * 256); // N
    float* dis_m = dis_g + N;                // N
    int* rp_g  = (int*)(dis_m + N);          // N+1
    int* rp_m  = rp_g + (N + 1);             // N+1
    int* cnt_g = rp_m + (N + 1);             // N
    int* cnt_m = cnt_g + N;                  // N
    int* col_g = cnt_m + N;                  // E
    int* col_m = col_g + E;                  // 2E
    int* bsum_g = col_m + 2 * (size_t)E;
    const int nb = (N + 255) / 256;
    int* bsum_m = bsum_g + nb;

    const int nwb = (N + 3) / 4;
    const int gmx = (N + 127) / 128;

    // --- degrees, normalizers, CSR build (XCD-partitioned scatter) ---
    hipMemsetAsync(cnt_g, 0, 2 * (size_t)N * sizeof(int), stream);
    deg_kernel<<<NPART * BPP, 256, 0, stream>>>(u, v, cnt_g, cnt_m, E, pdiv);
    dis_kernel<<<(N + 255) / 256, 256, 0, stream>>>(cnt_g, cnt_m, dis_g, dis_m, N);
    scan_reduce_kernel<<<nb, 256, 0, stream>>>(cnt_g, cnt_m, bsum_g, bsum_m, N);
    scan_bsum_kernel<<<1, 64, 0, stream>>>(bsum_g, bsum_m, nb);
    scan_final_kernel<<<nb, 256, 0, stream>>>(cnt_g, cnt_m, bsum_g, bsum_m, rp_g, rp_m, N);
    hipMemsetAsync(cnt_g, 0, 2 * (size_t)N * sizeof(int), stream);
    fill_kernel<<<NPART * BPP, 256, 0, stream>>>(u, v, rp_g, rp_m, cnt_g, cnt_m, col_g, col_m, E, pdiv);

    // --- weight casts (x cast fused into GEMM1) ---
    cast_wt_kernel<<<(256 * 256 + 255) / 256, 256, 0, stream>>>(W1, w1t, 256);
    cast_wt_kernel<<<(256 * 256 + 255) / 256, 256, 0, stream>>>(W2, w2t, 256);
    cast_wt_kernel<<<(64 * 256 + 255) / 256, 256, 0, stream>>>(Wp, wpt, 64);

    // --- conv1: h' = dis_g * (x @ W1); agg = relu(gather(h') + b1) ---
    mfma_gemm_kernel<128, true, false, true><<<dim3(gmx, 2), 256, 0, stream>>>(
        x, w1t, nullptr, dis_g, hb, N, HID);
    conv_gather_bf16<true><<<nwb, 256, 0, stream>>>(hb, dis_g, b1, rp_g, col_g, aggb, N);

    // --- conv2: h' = dis_g * (agg @ W2); agg = gather(h') + b2 ---
    mfma_gemm_kernel<128, true, false, false><<<dim3(gmx, 2), 256, 0, stream>>>(
        aggb, w2t, nullptr, dis_g, hb, N, HID);
    conv_gather_bf16<false><<<nwb, 256, 0, stream>>>(hb, dis_g, b2, rp_g, col_g, aggb, N);

    // --- projection: embA = bf16( dis_m * (agg @ Wp + bp) ) ---
    mfma_gemm_kernel<64, true, true, false><<<dim3(gmx, 1), 256, 0, stream>>>(
        aggb, wpt, bp, dis_m, embA, N, DOUT);

    // --- 2-hop MP: out = D A D^2 A (D emb); D-scales folded into epilogues ---
    mp_gather_bf16<2><<<nwb, 256, 0, stream>>>(embA, dis_m, rp_m, col_m, embB, N);
    mp_gather_bf16<1><<<nwb, 256, 0, stream>>>(embB, dis_m, rp_m, col_m, embA, N);

    // --- loss ---
    hipMemsetAsync(d_out, 0, sizeof(float), stream);
    loss_kernel<<<1024, 256, 0, stream>>>(embA, batch, (float*)d_out, B, 1.0f / (float)B);
}

// Round 6
// 756.164 us; speedup vs baseline: 9.1593x; 1.1195x over previous
//
#include <hip/hip_runtime.h>
#include <hip/hip_bf16.h>

#define DIN 256
#define HID 256
#define DOUT 64
#define NPART 8
#define BPP 128  // blocks per partition for deg/fill

typedef short short8 __attribute__((ext_vector_type(8)));
typedef float f32x4 __attribute__((ext_vector_type(4)));

__device__ __forceinline__ float b2f(ushort u) {
    unsigned int x = ((unsigned int)u) << 16;
    return __builtin_bit_cast(float, x);
}
__device__ __forceinline__ ushort f2bf(float f) {
    unsigned int u = __builtin_bit_cast(unsigned int, f);
    unsigned int r = (u + 0x7FFFu + ((u >> 16) & 1u)) >> 16;
    return (ushort)r;
}

// ---------------------------------------------------------------------------
// XCD-partitioned degree counting (block b owns node range part = b & 7 so
// each partition's counter lines are written from one XCD's L2).
__global__ __launch_bounds__(256) void deg_kernel(const int* __restrict__ u,
                                                  const int* __restrict__ v,
                                                  int* __restrict__ cnt_g,
                                                  int* __restrict__ cnt_m,
                                                  int E, unsigned pdiv) {
    const int part = blockIdx.x & (NPART - 1);
    const int stride = BPP * 256;
    for (int e = (blockIdx.x >> 3) * 256 + threadIdx.x; e < E; e += stride) {
        int a = u[e], b = v[e];
        unsigned pb = (unsigned)b / pdiv;
        unsigned pa = (unsigned)a / pdiv;
        if (pb == (unsigned)part) atomicAdd(&cnt_g[b], 1);
        if (a != b) {
            if (pb == (unsigned)part) atomicAdd(&cnt_m[b], 1);
            if (pa == (unsigned)part) atomicAdd(&cnt_m[a], 1);
        }
    }
}

__global__ __launch_bounds__(256) void dis_kernel(const int* __restrict__ cnt_g,
                                                  const int* __restrict__ cnt_m,
                                                  float* __restrict__ dis_g,
                                                  float* __restrict__ dis_m,
                                                  int N) {
    int i = blockIdx.x * blockDim.x + threadIdx.x;
    if (i >= N) return;
    dis_g[i] = rsqrtf((float)cnt_g[i] + 1.0f);
    int d = cnt_m[i];
    dis_m[i] = (d > 0) ? rsqrtf((float)d) : 0.0f;
}

// ---------------------------------------------------------------------------
// 3-phase exclusive scan for two int arrays at once.
__global__ __launch_bounds__(256) void scan_reduce_kernel(const int* __restrict__ a,
                                                          const int* __restrict__ b,
                                                          int* __restrict__ bsa,
                                                          int* __restrict__ bsb,
                                                          int N) {
    __shared__ int sa[256], sb[256];
    int i = blockIdx.x * 256 + threadIdx.x;
    sa[threadIdx.x] = (i < N) ? a[i] : 0;
    sb[threadIdx.x] = (i < N) ? b[i] : 0;
    __syncthreads();
    for (int s = 128; s > 0; s >>= 1) {
        if (threadIdx.x < s) {
            sa[threadIdx.x] += sa[threadIdx.x + s];
            sb[threadIdx.x] += sb[threadIdx.x + s];
        }
        __syncthreads();
    }
    if (threadIdx.x == 0) { bsa[blockIdx.x] = sa[0]; bsb[blockIdx.x] = sb[0]; }
}

__global__ void scan_bsum_kernel(int* __restrict__ bsa, int* __restrict__ bsb, int nb) {
    if (threadIdx.x == 0) {
        int acc = 0;
        for (int i = 0; i < nb; ++i) { int t = bsa[i]; bsa[i] = acc; acc += t; }
    }
    if (threadIdx.x == 1) {
        int acc = 0;
        for (int i = 0; i < nb; ++i) { int t = bsb[i]; bsb[i] = acc; acc += t; }
    }
}

__global__ __launch_bounds__(256) void scan_final_kernel(const int* __restrict__ a,
                                                         const int* __restrict__ b,
                                                         const int* __restrict__ bsa,
                                                         const int* __restrict__ bsb,
                                                         int* __restrict__ rpa,
                                                         int* __restrict__ rpb,
                                                         int N) {
    __shared__ int sa[256], sb[256];
    int i = blockIdx.x * 256 + threadIdx.x;
    sa[threadIdx.x] = (i < N) ? a[i] : 0;
    sb[threadIdx.x] = (i < N) ? b[i] : 0;
    __syncthreads();
    for (int off = 1; off < 256; off <<= 1) {
        int ta = (threadIdx.x >= off) ? sa[threadIdx.x - off] : 0;
        int tb = (threadIdx.x >= off) ? sb[threadIdx.x - off] : 0;
        __syncthreads();
        sa[threadIdx.x] += ta;
        sb[threadIdx.x] += tb;
        __syncthreads();
    }
    if (i < N) {
        rpa[i + 1] = bsa[blockIdx.x] + sa[threadIdx.x];
        rpb[i + 1] = bsb[blockIdx.x] + sb[threadIdx.x];
    }
    if (i == 0) { rpa[0] = 0; rpb[0] = 0; }
}

// ---------------------------------------------------------------------------
// XCD-partitioned CSR fill.
__global__ __launch_bounds__(256) void fill_kernel(const int* __restrict__ u,
                                                   const int* __restrict__ v,
                                                   const int* __restrict__ rp_g,
                                                   const int* __restrict__ rp_m,
                                                   int* __restrict__ cnt_g,
                                                   int* __restrict__ cnt_m,
                                                   int* __restrict__ col_g,
                                                   int* __restrict__ col_m,
                                                   int E, unsigned pdiv) {
    const int part = blockIdx.x & (NPART - 1);
    const int stride = BPP * 256;
    for (int e = (blockIdx.x >> 3) * 256 + threadIdx.x; e < E; e += stride) {
        int a = u[e], b = v[e];
        unsigned pb = (unsigned)b / pdiv;
        unsigned pa = (unsigned)a / pdiv;
        if (pb == (unsigned)part) {
            int p = rp_g[b] + atomicAdd(&cnt_g[b], 1);
            col_g[p] = a;
        }
        if (a != b) {
            if (pb == (unsigned)part) {
                int p1 = rp_m[b] + atomicAdd(&cnt_m[b], 1);
                col_m[p1] = a;
            }
            if (pa == (unsigned)part) {
                int p2 = rp_m[a] + atomicAdd(&cnt_m[a], 1);
                col_m[p2] = b;
            }
        }
    }
}

// ---------------------------------------------------------------------------
// W[K=256][NOUT] f32 -> Wt[NOUT][256] bf16 (plain transpose, no swizzle:
// the GEMM reads B straight from L2, no LDS).
__global__ __launch_bounds__(256) void cast_wt_kernel(const float* __restrict__ W,
                                                      ushort* __restrict__ Wt,
                                                      int NOUT) {
    int idx = blockIdx.x * 256 + threadIdx.x;
    if (idx >= NOUT * 256) return;
    int c = idx >> 8;
    int k = idx & 255;
    Wt[idx] = f2bf(W[k * NOUT + c]);
}

// ---------------------------------------------------------------------------
// bf16 MFMA GEMM, LDS-free. C[M x NTOT] = rowscale[row]*(A[M x 256] @ W + bias).
// B-fragments read directly from Wt (128 KB, L2-resident). A_F32: A is f32,
// converted to bf16 in-register (fuses the input cast).
template <int TN, bool OUT_BF16, bool ADD_BIAS, bool A_F32>
__global__ __launch_bounds__(256) void mfma_gemm_kernel(
    const void* __restrict__ A, const ushort* __restrict__ Bt,
    const float* __restrict__ bias, const float* __restrict__ rowscale,
    void* __restrict__ C, int M, int NTOT) {
    constexpr int BM = 128;
    constexpr int FM = (TN == 128) ? 4 : 2;
    constexpr int FN = 4;
    const int tid = threadIdx.x;
    const int w = tid >> 6;
    const int lane = tid & 63;
    const int row0 = blockIdx.x * BM;
    const int col0 = blockIdx.y * TN;
    const int wrow = (TN == 128) ? ((w >> 1) * 64) : (w * 32);
    const int wcol = (TN == 128) ? ((w & 1) * 64) : 0;
    const int g = lane >> 4;
    const int r15 = lane & 15;

    f32x4 acc[FM][FN];
#pragma unroll
    for (int m = 0; m < FM; ++m)
#pragma unroll
        for (int n = 0; n < FN; ++n) acc[m][n] = {0.f, 0.f, 0.f, 0.f};

    const void* arow[FM];
#pragma unroll
    for (int m = 0; m < FM; ++m) {
        int r = row0 + wrow + m * 16 + r15;
        r = (r < M) ? r : (M - 1);
        if (A_F32)
            arow[m] = (const void*)((const float*)A + (size_t)r * 256 + g * 8);
        else
            arow[m] = (const void*)((const ushort*)A + (size_t)r * 256 + g * 8);
    }
    const ushort* brow[FN];
#pragma unroll
    for (int n = 0; n < FN; ++n)
        brow[n] = Bt + (size_t)(col0 + wcol + n * 16 + r15) * 256 + g * 8;

#pragma unroll
    for (int ks = 0; ks < 8; ++ks) {
        short8 a[FM], b[FN];
#pragma unroll
        for (int m = 0; m < FM; ++m) {
            if (A_F32) {
                const float* ap = (const float*)arow[m] + ks * 32;
                float4 f0 = *(const float4*)ap;
                float4 f1 = *(const float4*)(ap + 4);
                short8 t;
                t[0] = (short)f2bf(f0.x); t[1] = (short)f2bf(f0.y);
                t[2] = (short)f2bf(f0.z); t[3] = (short)f2bf(f0.w);
                t[4] = (short)f2bf(f1.x); t[5] = (short)f2bf(f1.y);
                t[6] = (short)f2bf(f1.z); t[7] = (short)f2bf(f1.w);
                a[m] = t;
            } else {
                a[m] = *(const short8*)((const ushort*)arow[m] + ks * 32);
            }
        }
#pragma unroll
        for (int n = 0; n < FN; ++n)
            b[n] = *(const short8*)(brow[n] + ks * 32);
#pragma unroll
        for (int m = 0; m < FM; ++m)
#pragma unroll
            for (int n = 0; n < FN; ++n)
                acc[m][n] = __builtin_amdgcn_mfma_f32_16x16x32_bf16(a[m], b[n], acc[m][n], 0, 0, 0);
    }

#pragma unroll
    for (int m = 0; m < FM; ++m) {
        int rbase = row0 + wrow + m * 16 + g * 4;
#pragma unroll
        for (int j = 0; j < 4; ++j) {
            int grow = rbase + j;
            if (grow >= M) continue;
            float rs = rowscale[grow];
#pragma unroll
            for (int n = 0; n < FN; ++n) {
                int gcol = col0 + wcol + n * 16 + r15;
                float vv = acc[m][n][j];
                if (ADD_BIAS) vv += bias[gcol];
                vv *= rs;
                if (OUT_BF16)
                    ((ushort*)C)[(size_t)grow * NTOT + gcol] = f2bf(vv);
                else
                    ((float*)C)[(size_t)grow * NTOT + gcol] = vv;
            }
        }
    }
}

// ---------------------------------------------------------------------------
// GCN aggregation gather (bf16 rows, f32 accum), edge loop unrolled x4 for
// memory-level parallelism (4 neighbor rows in flight). h' pre-scaled by dis:
// out[i] = act( dis[i] * (h'[i] + sum_{u in N(i)} h'[u]) + bias )
template <bool RELU>
__global__ __launch_bounds__(256) void conv_gather_bf16(const ushort* __restrict__ h,
                                                        const float* __restrict__ dis,
                                                        const float* __restrict__ bias,
                                                        const int* __restrict__ rp,
                                                        const int* __restrict__ col,
                                                        ushort* __restrict__ out,
                                                        int N) {
    int wid = (blockIdx.x * blockDim.x + threadIdx.x) >> 6;
    int lane = threadIdx.x & 63;
    if (wid >= N) return;
    const ushort4* h4 = (const ushort4*)h;
    ushort4 sv = h4[(size_t)wid * 64 + lane];
    float a0 = b2f(sv.x), a1 = b2f(sv.y), a2 = b2f(sv.z), a3 = b2f(sv.w);
    int e0 = rp[wid], e1 = rp[wid + 1];
    int e = e0;
    for (; e + 3 < e1; e += 4) {
        int s0 = col[e], s1 = col[e + 1], s2 = col[e + 2], s3 = col[e + 3];
        ushort4 n0 = h4[(size_t)s0 * 64 + lane];
        ushort4 n1 = h4[(size_t)s1 * 64 + lane];
        ushort4 n2 = h4[(size_t)s2 * 64 + lane];
        ushort4 n3 = h4[(size_t)s3 * 64 + lane];
        a0 += b2f(n0.x) + b2f(n1.x) + b2f(n2.x) + b2f(n3.x);
        a1 += b2f(n0.y) + b2f(n1.y) + b2f(n2.y) + b2f(n3.y);
        a2 += b2f(n0.z) + b2f(n1.z) + b2f(n2.z) + b2f(n3.z);
        a3 += b2f(n0.w) + b2f(n1.w) + b2f(n2.w) + b2f(n3.w);
    }
    for (; e < e1; ++e) {
        int s = col[e];
        ushort4 nv = h4[(size_t)s * 64 + lane];
        a0 += b2f(nv.x); a1 += b2f(nv.y); a2 += b2f(nv.z); a3 += b2f(nv.w);
    }
    float di = dis[wid];
    float4 bv = ((const float4*)bias)[lane];
    float o0 = di * a0 + bv.x;
    float o1 = di * a1 + bv.y;
    float o2 = di * a2 + bv.z;
    float o3 = di * a3 + bv.w;
    if (RELU) {
        o0 = fmaxf(o0, 0.f); o1 = fmaxf(o1, 0.f);
        o2 = fmaxf(o2, 0.f); o3 = fmaxf(o3, 0.f);
    }
    ushort4 ov;
    ov.x = f2bf(o0); ov.y = f2bf(o1); ov.z = f2bf(o2); ov.w = f2bf(o3);
    ((ushort4*)out)[(size_t)wid * 64 + lane] = ov;
}

// Message-passing gather, bf16 rows (128 B), f32 accum, unrolled x4 per half
// (8 rows in flight per wave). Lanes 0-31: even list slots; 32-63: odd.
template <int POW>
__global__ __launch_bounds__(256) void mp_gather_bf16(const ushort* __restrict__ in,
                                                      const float* __restrict__ dis,
                                                      const int* __restrict__ rp,
                                                      const int* __restrict__ col,
                                                      ushort* __restrict__ out,
                                                      int N) {
    int wid = (blockIdx.x * blockDim.x + threadIdx.x) >> 6;
    int lane = threadIdx.x & 63;
    if (wid >= N) return;
    const int half = lane >> 5;
    const int l2 = lane & 31;
    float a0 = 0.f, a1 = 0.f;
    int e0 = rp[wid], e1 = rp[wid + 1];
    int e = e0 + half;
    for (; e + 6 < e1; e += 8) {
        int s0 = col[e], s1 = col[e + 2], s2 = col[e + 4], s3 = col[e + 6];
        ushort2 n0 = *(const ushort2*)(in + (size_t)s0 * DOUT + l2 * 2);
        ushort2 n1 = *(const ushort2*)(in + (size_t)s1 * DOUT + l2 * 2);
        ushort2 n2 = *(const ushort2*)(in + (size_t)s2 * DOUT + l2 * 2);
        ushort2 n3 = *(const ushort2*)(in + (size_t)s3 * DOUT + l2 * 2);
        a0 += b2f(n0.x) + b2f(n1.x) + b2f(n2.x) + b2f(n3.x);
        a1 += b2f(n0.y) + b2f(n1.y) + b2f(n2.y) + b2f(n3.y);
    }
    for (; e < e1; e += 2) {
        int s = col[e];
        ushort2 nv = *(const ushort2*)(in + (size_t)s * DOUT + l2 * 2);
        a0 += b2f(nv.x);
        a1 += b2f(nv.y);
    }
    a0 += __shfl_xor(a0, 32);
    a1 += __shfl_xor(a1, 32);
    if (half == 0) {
        float d = dis[wid];
        float sc = (POW == 2) ? d * d : d;
        ushort2 ov;
        ov.x = f2bf(sc * a0);
        ov.y = f2bf(sc * a1);
        *(ushort2*)(out + (size_t)wid * DOUT + l2 * 2) = ov;
    }
}

// ---------------------------------------------------------------------------
// Loss: half-wave per triplet (bf16 emb rows, ushort2 per lane = 4 B).
__global__ __launch_bounds__(256) void loss_kernel(const ushort* __restrict__ emb,
                                                   const int* __restrict__ batch,
                                                   float* __restrict__ out,
                                                   int B, float invB) {
    const int nhw = gridDim.x * 8;
    const int hwid = blockIdx.x * 8 + (threadIdx.x >> 5);
    const int l2 = threadIdx.x & 31;
    float lsum = 0.0f;
    for (int r = hwid; r < B; r += nhw) {
        int a = batch[r * 3 + 0];
        int p = batch[r * 3 + 1];
        int ng = batch[r * 3 + 2];
        ushort2 wa = *(const ushort2*)(emb + (size_t)a * DOUT + l2 * 2);
        ushort2 wp = *(const ushort2*)(emb + (size_t)p * DOUT + l2 * 2);
        ushort2 wn = *(const ushort2*)(emb + (size_t)ng * DOUT + l2 * 2);
        float va0 = b2f(wa.x), va1 = b2f(wa.y);
        float vp0 = b2f(wp.x), vp1 = b2f(wp.y);
        float vn0 = b2f(wn.x), vn1 = b2f(wn.y);
        float aa = va0 * va0 + va1 * va1;
        float pp = vp0 * vp0 + vp1 * vp1;
        float nn = vn0 * vn0 + vn1 * vn1;
        float ap = va0 * vp0 + va1 * vp1;
        float an = va0 * vn0 + va1 * vn1;
#pragma unroll
        for (int off = 16; off > 0; off >>= 1) {
            aa += __shfl_xor(aa, off);
            pp += __shfl_xor(pp, off);
            nn += __shfl_xor(nn, off);
            ap += __shfl_xor(ap, off);
            an += __shfl_xor(an, off);
        }
        if (l2 == 0) {
            float na = fmaxf(sqrtf(aa), 1e-8f);
            float npp = fmaxf(sqrtf(pp), 1e-8f);
            float nnn = fmaxf(sqrtf(nn), 1e-8f);
            float cx = ap / (na * npp);
            float cy = an / (na * nnn);
            lsum += log1pf(expf((cy - cx) * 5.0f));  // 1/TEMP = 5
        }
    }
    __shared__ float part[8];
    if (l2 == 0) part[threadIdx.x >> 5] = lsum;
    __syncthreads();
    if (threadIdx.x == 0) {
        float s = 0.f;
#pragma unroll
        for (int i = 0; i < 8; ++i) s += part[i];
        atomicAdd(out, s * invB);
    }
}

// ---------------------------------------------------------------------------
extern "C" void kernel_launch(void* const* d_in, const int* in_sizes, int n_in,
                              void* d_out, int out_size, void* d_ws, size_t ws_size,
                              hipStream_t stream) {
    const float* x   = (const float*)d_in[0];
    const int* ei    = (const int*)d_in[1];
    const int* batch = (const int*)d_in[2];
    const float* W1  = (const float*)d_in[3];
    const float* b1  = (const float*)d_in[4];
    const float* W2  = (const float*)d_in[5];
    const float* b2  = (const float*)d_in[6];
    const float* Wp  = (const float*)d_in[7];
    const float* bp  = (const float*)d_in[8];
    const int N = in_sizes[0] / DIN;
    const int E = in_sizes[1] / 2;
    const int B = in_sizes[2] / 3;
    const int* u = ei;
    const int* v = ei + E;
    const unsigned pdiv = (unsigned)((N + NPART - 1) / NPART);

    // --- workspace layout ---
    ushort* hb   = (ushort*)d_ws;            // N*256 bf16
    ushort* aggb = hb + (size_t)N * 256;     // N*256 bf16
    ushort* embA = aggb + (size_t)N * 256;   // N*64 bf16
    ushort* embB = embA + (size_t)N * DOUT;  // N*64 bf16
    ushort* w1t  = embB + (size_t)N * DOUT;  // 256*256
    ushort* w2t  = w1t + 256 * 256;          // 256*256
    ushort* wpt  = w2t + 256 * 256;          // 64*256
    float* dis_g = (float*)(wpt + 64 * 256); // N
    float* dis_m = dis_g + N;                // N
    int* rp_g  = (int*)(dis_m + N);          // N+1
    int* rp_m  = rp_g + (N + 1);             // N+1
    int* cnt_g = rp_m + (N + 1);             // N
    int* cnt_m = cnt_g + N;                  // N
    int* col_g = cnt_m + N;                  // E
    int* col_m = col_g + E;                  // 2E
    int* bsum_g = col_m + 2 * (size_t)E;
    const int nb = (N + 255) / 256;
    int* bsum_m = bsum_g + nb;

    const int nwb = (N + 3) / 4;
    const int gmx = (N + 127) / 128;

    // --- degrees, normalizers, CSR build (XCD-partitioned scatter) ---
    hipMemsetAsync(cnt_g, 0, 2 * (size_t)N * sizeof(int), stream);
    deg_kernel<<<NPART * BPP, 256, 0, stream>>>(u, v, cnt_g, cnt_m, E, pdiv);
    dis_kernel<<<(N + 255) / 256, 256, 0, stream>>>(cnt_g, cnt_m, dis_g, dis_m, N);
    scan_reduce_kernel<<<nb, 256, 0, stream>>>(cnt_g, cnt_m, bsum_g, bsum_m, N);
    scan_bsum_kernel<<<1, 64, 0, stream>>>(bsum_g, bsum_m, nb);
    scan_final_kernel<<<nb, 256, 0, stream>>>(cnt_g, cnt_m, bsum_g, bsum_m, rp_g, rp_m, N);
    hipMemsetAsync(cnt_g, 0, 2 * (size_t)N * sizeof(int), stream);
    fill_kernel<<<NPART * BPP, 256, 0, stream>>>(u, v, rp_g, rp_m, cnt_g, cnt_m, col_g, col_m, E, pdiv);

    // --- weight casts (x cast fused into GEMM1) ---
    cast_wt_kernel<<<(256 * 256 + 255) / 256, 256, 0, stream>>>(W1, w1t, 256);
    cast_wt_kernel<<<(256 * 256 + 255) / 256, 256, 0, stream>>>(W2, w2t, 256);
    cast_wt_kernel<<<(64 * 256 + 255) / 256, 256, 0, stream>>>(Wp, wpt, 64);

    // --- conv1: h' = dis_g * (x @ W1); agg = relu(gather(h') + b1) ---
    mfma_gemm_kernel<128, true, false, true><<<dim3(gmx, 2), 256, 0, stream>>>(
        x, w1t, nullptr, dis_g, hb, N, HID);
    conv_gather_bf16<true><<<nwb, 256, 0, stream>>>(hb, dis_g, b1, rp_g, col_g, aggb, N);

    // --- conv2: h' = dis_g * (agg @ W2); agg = gather(h') + b2 ---
    mfma_gemm_kernel<128, true, false, false><<<dim3(gmx, 2), 256, 0, stream>>>(
        aggb, w2t, nullptr, dis_g, hb, N, HID);
    conv_gather_bf16<false><<<nwb, 256, 0, stream>>>(hb, dis_g, b2, rp_g, col_g, aggb, N);

    // --- projection: embA = bf16( dis_m * (agg @ Wp + bp) ) ---
    mfma_gemm_kernel<64, true, true, false><<<dim3(gmx, 1), 256, 0, stream>>>(
        aggb, wpt, bp, dis_m, embA, N, DOUT);

    // --- 2-hop MP: out = D A D^2 A (D emb); D-scales folded into epilogues ---
    mp_gather_bf16<2><<<nwb, 256, 0, stream>>>(embA, dis_m, rp_m, col_m, embB, N);
    mp_gather_bf16<1><<<nwb, 256, 0, stream>>>(embB, dis_m, rp_m, col_m, embA, N);

    // --- loss ---
    hipMemsetAsync(d_out, 0, sizeof(float), stream);
    loss_kernel<<<1024, 256, 0, stream>>>(embA, batch, (float*)d_out, B, 1.0f / (float)B);
}